// Round 1
// baseline (241.377 us; speedup 1.0000x reference)
//
#include <hip/hip_runtime.h>

typedef short short8 __attribute__((ext_vector_type(8)));
typedef float f32x4 __attribute__((ext_vector_type(4)));

#define NRAYS 16384
#define NS    128
#define INV2PI 0.15915494309189535f
#define LOG2E  1.4426950408889634f

// ws layout (bytes):
//   [0,8192)      W1f  u16[4096]  frag: elem(q,n,j)=W1[k=q*8+j][n]
//   [8192,16384)  W2f  u16[4096]
//   [16384,18432) Wof  u16[1024]  fused head: n=0 sigma, n=1..3 W_out[:,1:]@W_rgb
//   [18432,19008) wsf  float[144] (F_* indices)
#define F_B1   0
#define F_B2   64
#define F_BO4  128   // {b_out[0], bc0, bc1, bc2}
#define F_DT   132   // finalized dt = mean(tmax-tmin)/S  (prep block 3)
#define F_ISBF 133   // int: input dtype flag (prep block 3)

__device__ __forceinline__ float bf2f(unsigned short u){
  union { unsigned int i; float f; } v; v.i = ((unsigned int)u) << 16; return v.f;
}
__device__ __forceinline__ unsigned short f2bf(float f){   // RNE
  union { unsigned int i; float f; } v; v.f = f;
  unsigned int i = v.i;
  unsigned int r = i + 0x7FFFu + ((i >> 16) & 1u);
  return (unsigned short)(r >> 16);
}
// hardware packed f32x2 -> bf16x2 (RNE, single VOP3)
__device__ __forceinline__ unsigned cvtpk(float a, float b){
  unsigned r; asm("v_cvt_pk_bf16_f32 %0, %1, %2" : "=v"(r) : "v"(a), "v"(b));
  return r;
}
__device__ __forceinline__ float ldin(const void* p, int i, int isbf){
  return isbf ? bf2f(((const unsigned short*)p)[i]) : ((const float*)p)[i];
}
// input dtype detection: even u16 halves of tmn are ~2.0 iff inputs are bf16
__device__ __forceinline__ int detect_bf(const void* tmn){
  const unsigned short* q = (const unsigned short*)tmn;
  int ok = 1;
  #pragma unroll
  for (int i = 0; i < 8; i++){
    float v = bf2f(q[2*i]);
    ok &= (v > 1.5f && v < 2.7f) ? 1 : 0;
  }
  return ok;
}
__device__ __forceinline__ float hw_fract(float x){ float r; asm("v_fract_f32 %0, %1":"=v"(r):"v"(x)); return r; }
__device__ __forceinline__ float hw_sin(float rev){ float f = hw_fract(rev); float r; asm("v_sin_f32 %0, %1":"=v"(r):"v"(f)); return r; }
__device__ __forceinline__ float hw_exp2(float x){ float r; asm("v_exp_f32 %0, %1":"=v"(r):"v"(x)); return r; }
__device__ __forceinline__ float hw_rcp(float x){ float r; asm("v_rcp_f32 %0, %1":"=v"(r):"v"(x)); return r; }
__device__ __forceinline__ float sigmoidf_hw(float a){
  return hw_rcp(1.f + hw_exp2(-a * LOG2E));
}
// wave64 sum-reduce entirely in the VALU pipe (DPP); total lands in lane 63.
__device__ __forceinline__ float dpp_reduce_add(float x){
  float t;
  asm("v_add_f32 %0, %1, %1 row_shr:1 bound_ctrl:0"  : "=v"(t) : "v"(x));
  asm("v_add_f32 %0, %1, %1 row_shr:2 bound_ctrl:0"  : "=v"(x) : "v"(t));
  asm("v_add_f32 %0, %1, %1 row_shr:4 bound_ctrl:0"  : "=v"(t) : "v"(x));
  asm("v_add_f32 %0, %1, %1 row_shr:8 bound_ctrl:0"  : "=v"(x) : "v"(t));
  asm("v_add_f32 %0, %1, %1 row_bcast:15 row_mask:0xa bound_ctrl:0" : "=v"(t) : "v"(x));
  asm("v_add_f32 %0, %1, %1 row_bcast:31 row_mask:0xc bound_ctrl:0" : "=v"(x) : "v"(t));
  return x;   // valid in lane 63 only
}

// Prep: 4 blocks. b0/b1 -> W1f/W2f frags, b2 -> fused head + biases,
// b3 -> full dt reduction (16384 elems, one block) + dtype flag.
// Finalizing dt here removes the 64-partial load + 6-step DPP chain from
// every one of the 16384 main blocks (and ~4 MB/dispatch of HBM fetch).
__global__ void nerf_prep(const void* __restrict__ tmn, const void* __restrict__ tmx,
                          const void* __restrict__ W1, const void* __restrict__ W2,
                          const void* __restrict__ Wout, const void* __restrict__ b1,
                          const void* __restrict__ b2, const void* __restrict__ bout,
                          const void* __restrict__ Wrgb, const void* __restrict__ brgb,
                          void* __restrict__ ws)
{
  const int tid = threadIdx.x;
  const int b   = blockIdx.x;
  const int isbf = detect_bf(tmn);
  unsigned short* w1f = (unsigned short*)ws;
  unsigned short* w2f = w1f + 4096;
  unsigned short* wof = w1f + 8192;
  float* wsf = (float*)((char*)ws + 18432);

  if (b == 0){
    for (int e = tid; e < 4096; e += 256){
      int j = e & 7, n = (e >> 3) & 63, q = e >> 9;
      int k = q*8 + j;
      w1f[e] = (k < 63) ? f2bf(ldin(W1, k*64 + n, isbf)) : (unsigned short)0;
    }
  } else if (b == 1){
    for (int e = tid; e < 4096; e += 256){
      int j = e & 7, n = (e >> 3) & 63, q = e >> 9;
      int k = q*8 + j;
      w2f[e] = f2bf(ldin(W2, k*64 + n, isbf));
    }
  } else if (b == 2){
    for (int e = tid; e < 1024; e += 256){
      int j = e & 7, n = (e >> 3) & 15, q = e >> 7;
      int k = q*8 + j;
      float v = 0.f;
      if (n == 0) v = ldin(Wout, k*17 + 0, isbf);
      else if (n < 4){
        int c = n - 1;
        #pragma unroll
        for (int jj = 0; jj < 16; jj++)
          v += ldin(Wout, k*17 + 1 + jj, isbf) * ldin(Wrgb, jj*3 + c, isbf);
      }
      wof[e] = f2bf(v);
    }
    if (tid < 64){
      wsf[F_B1 + tid] = ldin(b1, tid, isbf);
      wsf[F_B2 + tid] = ldin(b2, tid, isbf);
    }
    if (tid >= 64 && tid < 67){
      int c = tid - 64;
      float v = ldin(brgb, c, isbf);
      #pragma unroll
      for (int jj = 0; jj < 16; jj++)
        v += ldin(bout, 1 + jj, isbf) * ldin(Wrgb, jj*3 + c, isbf);
      wsf[F_BO4 + 1 + c] = v;
    }
    if (tid == 67) wsf[F_BO4] = ldin(bout, 0, isbf);
  } else {
    float s = 0.f;
    for (int i = tid; i < NRAYS; i += 256)
      s += ldin(tmx, i, isbf) - ldin(tmn, i, isbf);
    #pragma unroll
    for (int off = 32; off >= 1; off >>= 1) s += __shfl_down(s, off, 64);
    __shared__ float acc[4];
    if ((tid & 63) == 0) acc[tid >> 6] = s;
    __syncthreads();
    if (tid == 0){
      wsf[F_DT] = (acc[0] + acc[1] + acc[2] + acc[3]) *
                  (1.0f / ((float)NRAYS * (float)NS));
      ((int*)wsf)[F_ISBF] = isbf;
    }
  }
}

// Block = 256 threads = 4 waves = 1 ray. Arena [q=8][m=128][j=8] bf16 = 16 KB.
// Occupancy: 8 blocks/CU (2048-thread cap) x 4 waves = 32 waves/CU = 100% HW
// cap (LDS 128/160 KB), vs the old 128-thread layout's 20 waves/CU LDS cap.
// The kernel is latency-bound (per-SIMD issue pressure ~35%), so residency is
// the lever. Each wave owns a 32-row GEMM strip (m0 = wid*32): all layer
// D-writes and next-layer B-reads stay wave-private, so the barrier-free
// layer chain is preserved. One new barrier after enc (waves 2/3 read rows
// written by waves 0/1).
__global__ __launch_bounds__(256, 8)
void nerf_main(const void* __restrict__ ox, const void* __restrict__ oy,
               const void* __restrict__ oz, const void* __restrict__ dx,
               const void* __restrict__ dy, const void* __restrict__ dz,
               const void* __restrict__ tmn, const void* __restrict__ tmx,
               const void* __restrict__ ws, void* __restrict__ out)
{
  __shared__ __align__(16) char arena[16384];  // bf16 act -> fp32 O overlay (slab0)

  const int tid  = threadIdx.x;
  const int wid  = tid >> 6;
  const int lane = tid & 63;
  const int quad = lane >> 4;
  const int col  = lane & 15;
  const int m0   = wid * 32;

  const unsigned short* gW  = (const unsigned short*)ws;
  const float* wsf = (const float*)((const char*)ws + 18432);
  const int   isbf = ((const int*)wsf)[F_ISBF];
  const float dtv  = wsf[F_DT];

  const int ray = blockIdx.x;
  unsigned short* sA = (unsigned short*)arena;   // idx (q*128+m)*8+j

  // ---- positional encoding: threads 0..127 handle sample=tid ----
  if (tid < 128){
    float tmin = ldin(tmn, ray, isbf);
    float tmax = ldin(tmx, ray, isbf);
    float t = tmin + ((float)tid * (1.0f/127.0f)) * (tmax - tmin);
    float p[3];
    p[0] = ldin(ox, ray, isbf) + ldin(dx, ray, isbf) * t;
    p[1] = ldin(oy, ray, isbf) + ldin(dy, ray, isbf) * t;
    p[2] = ldin(oz, ray, isbf) + ldin(dz, ray, isbf) * t;
    float enc[64];
    enc[0] = p[0]; enc[1] = p[1]; enc[2] = p[2]; enc[63] = 0.f;
    #pragma unroll
    for (int c = 0; c < 3; c++){
      float rv = p[c] * INV2PI;
      const int bix = 3 + c*20;
      float sv = hw_sin(rv);
      float cv = hw_sin(rv + 0.25f);
      enc[bix] = sv; enc[bix+10] = cv;
      #pragma unroll
      for (int l = 1; l < 10; l++){
        float s2 = 2.f*sv*cv;
        float c2 = cv*cv - sv*sv;
        enc[bix+l] = s2; enc[bix+10+l] = c2;
        sv = s2; cv = c2;
      }
    }
    #pragma unroll
    for (int q = 0; q < 8; q++){
      uint4 w;
      w.x = cvtpk(enc[q*8+0], enc[q*8+1]);
      w.y = cvtpk(enc[q*8+2], enc[q*8+3]);
      w.z = cvtpk(enc[q*8+4], enc[q*8+5]);
      w.w = cvtpk(enc[q*8+6], enc[q*8+7]);
      *(uint4*)(sA + (q*128 + tid)*8) = w;
    }
  }
  __syncthreads();   // waves 2/3 read enc rows written by waves 0/1

  // ---- hidden layers: weights direct from global (L1-hot), bias in C-init ----
  #pragma unroll
  for (int layer = 0; layer < 2; layer++){
    const unsigned short* Wf = gW + layer*4096;
    const float* bptr = wsf + (layer ? F_B2 : F_B1);
    short8 wf[8];
    f32x4 bia[4];
    #pragma unroll
    for (int nt = 0; nt < 4; nt++){
      wf[nt*2]   = *(const short8*)(Wf + ((quad    )*64 + nt*16 + col)*8);
      wf[nt*2+1] = *(const short8*)(Wf + ((quad + 4)*64 + nt*16 + col)*8);
      bia[nt]    = *(const f32x4*)(bptr + nt*16 + quad*4);
    }
    #pragma unroll
    for (int mt = 0; mt < 2; mt++){
      const int m = m0 + mt*16 + col;
      short8 h0 = *(const short8*)(sA + ((quad    )*128 + m)*8);
      short8 h1 = *(const short8*)(sA + ((quad + 4)*128 + m)*8);
      #pragma unroll
      for (int nt = 0; nt < 4; nt++){
        f32x4 c = bia[nt];
        c = __builtin_amdgcn_mfma_f32_16x16x32_bf16(wf[nt*2],   h0, c, 0, 0, 0);
        c = __builtin_amdgcn_mfma_f32_16x16x32_bf16(wf[nt*2+1], h1, c, 0, 0, 0);
        uint2 pw;
        pw.x = cvtpk(fmaxf(c[0], 0.f), fmaxf(c[1], 0.f));
        pw.y = cvtpk(fmaxf(c[2], 0.f), fmaxf(c[3], 0.f));
        const int qw = nt*2 + (quad >> 1);
        *(uint2*)(sA + (qw*128 + m)*8 + (quad & 1)*4) = pw;
      }
    }
    // no barrier between layers: rows are wave-private
  }

  // ---- fused output head: 64 -> {sigma_pre, r_pre, g_pre, b_pre} ----
  {
    const unsigned short* Wo = gW + 8192;
    short8 wo0 = *(const short8*)(Wo + ((quad    )*16 + col)*8);
    short8 wo1 = *(const short8*)(Wo + ((quad + 4)*16 + col)*8);
    f32x4 bo4 = {0.f, 0.f, 0.f, 0.f};
    if (quad == 0) bo4 = *(const f32x4*)(wsf + F_BO4);
    float* Of = (float*)arena;            // overlays slab0 (read-before-write per mt)
    #pragma unroll
    for (int mt = 0; mt < 2; mt++){
      const int m = m0 + mt*16 + col;
      short8 h0 = *(const short8*)(sA + ((quad    )*128 + m)*8);
      short8 h1 = *(const short8*)(sA + ((quad + 4)*128 + m)*8);
      f32x4 c = bo4;
      c = __builtin_amdgcn_mfma_f32_16x16x32_bf16(wo0, h0, c, 0, 0, 0);
      c = __builtin_amdgcn_mfma_f32_16x16x32_bf16(wo1, h1, c, 0, 0, 0);
      if (quad == 0) *(f32x4*)(Of + m*4) = c;
    }
  }
  __syncthreads();   // all head LDS reads done before aux overlays slab2

  // ---- per-sample epilogue (threads 0..127 = samples; dt precomputed) ----
  const float* Of = (const float*)arena;
  float* aux = (float*)(arena + 4096);   // dead slab2: [0]=P0, [4..11]=xr, [12]=Tout
  float v = 0.f, alpha = 0.f, rc = 0.f, gc = 0.f, bc = 0.f;
  if (tid < 128){
    f32x4 o = *(const f32x4*)(Of + tid*4);
    float sigma = fmaxf(o[0], 0.f);
    float e2 = hw_exp2(-sigma * dtv * LOG2E);    // = 1 - alpha
    alpha = 1.f - e2;
    rc = sigmoidf_hw(o[1]);
    gc = sigmoidf_hw(o[2]);
    bc = sigmoidf_hw(o[3]);

    v = e2 + 1e-10f;
    #pragma unroll
    for (int off = 1; off < 64; off <<= 1){
      float tt = __shfl_up(v, off, 64);
      v = (lane >= off) ? v * tt : v;
    }
    if (wid == 0 && lane == 63) aux[0] = v;      // product of first 64 samples
  }
  __syncthreads();
  if (tid < 128){
    const float P0 = aux[0];
    float vfull = wid ? v * P0 : v;              // inclusive cumprod over full ray
    float tp = __shfl_up(vfull, 1, 64);
    float T = (lane == 0) ? (wid ? P0 : 1.f) : tp;
    float w = (T > 1e-4f) ? T * alpha : 0.f;
    float sr = dpp_reduce_add(w * rc);           // totals in lane 63
    float sg = dpp_reduce_add(w * gc);
    float sb = dpp_reduce_add(w * bc);
    if (lane == 63){
      aux[4 + wid*4] = sr; aux[5 + wid*4] = sg; aux[6 + wid*4] = sb;
      if (wid == 1) aux[12] = vfull;             // trans[:, -1]
    }
  }
  __syncthreads();
  if (tid == 0){
    float rr = aux[4] + aux[8], gg = aux[5] + aux[9], bb = aux[6] + aux[10];
    float Tout = aux[12];
    if (isbf){
      unsigned short* ob = (unsigned short*)out;
      ob[ray*3 + 0]     = f2bf(rr);
      ob[ray*3 + 1]     = f2bf(gg);
      ob[ray*3 + 2]     = f2bf(bb);
      ob[3*NRAYS + ray] = f2bf(Tout);
    } else {
      float* of = (float*)out;
      of[ray*3 + 0]     = rr;
      of[ray*3 + 1]     = gg;
      of[ray*3 + 2]     = bb;
      of[3*NRAYS + ray] = Tout;
    }
  }
}

extern "C" void kernel_launch(void* const* d_in, const int* in_sizes, int n_in,
                              void* d_out, int out_size, void* d_ws, size_t ws_size,
                              hipStream_t stream)
{
  nerf_prep<<<4, 256, 0, stream>>>(d_in[6], d_in[7], d_in[8], d_in[10], d_in[12],
                                   d_in[9], d_in[11], d_in[13], d_in[14], d_in[15],
                                   d_ws);
  nerf_main<<<NRAYS, 256, 0, stream>>>(d_in[0], d_in[1], d_in[2], d_in[3],
                                       d_in[4], d_in[5], d_in[6], d_in[7],
                                       d_ws, d_out);
}

// Round 2
// 171.423 us; speedup vs baseline: 1.4081x; 1.4081x over previous
//
#include <hip/hip_runtime.h>

typedef short short8 __attribute__((ext_vector_type(8)));
typedef float f32x4 __attribute__((ext_vector_type(4)));

#define NRAYS 16384
#define NS    128
#define INV2PI 0.15915494309189535f
#define LOG2E  1.4426950408889634f

// ws layout (bytes):
//   [0,8192)      W1f  u16[4096]  frag: elem(q,n,j)=W1[k=q*8+j][n]
//   [8192,16384)  W2f  u16[4096]
//   [16384,18432) Wof  u16[1024]  fused head: n=0 sigma, n=1..3 W_out[:,1:]@W_rgb
//   [18432,19008) wsf  float[144] (F_* indices)
#define F_B1   0
#define F_B2   64
#define F_BO4  128   // {b_out[0], bc0, bc1, bc2}
#define F_DT   132   // finalized dt = mean(tmax-tmin)/S  (prep block 3)
#define F_ISBF 133   // int: input dtype flag (prep block 3)

__device__ __forceinline__ float bf2f(unsigned short u){
  union { unsigned int i; float f; } v; v.i = ((unsigned int)u) << 16; return v.f;
}
__device__ __forceinline__ unsigned short f2bf(float f){   // RNE
  union { unsigned int i; float f; } v; v.f = f;
  unsigned int i = v.i;
  unsigned int r = i + 0x7FFFu + ((i >> 16) & 1u);
  return (unsigned short)(r >> 16);
}
// hardware packed f32x2 -> bf16x2 (RNE, single VOP3)
__device__ __forceinline__ unsigned cvtpk(float a, float b){
  unsigned r; asm("v_cvt_pk_bf16_f32 %0, %1, %2" : "=v"(r) : "v"(a), "v"(b));
  return r;
}
__device__ __forceinline__ float ldin(const void* p, int i, int isbf){
  return isbf ? bf2f(((const unsigned short*)p)[i]) : ((const float*)p)[i];
}
// input dtype detection: even u16 halves of tmn are ~2.0 iff inputs are bf16
__device__ __forceinline__ int detect_bf(const void* tmn){
  const unsigned short* q = (const unsigned short*)tmn;
  int ok = 1;
  #pragma unroll
  for (int i = 0; i < 8; i++){
    float v = bf2f(q[2*i]);
    ok &= (v > 1.5f && v < 2.7f) ? 1 : 0;
  }
  return ok;
}
__device__ __forceinline__ float hw_fract(float x){ float r; asm("v_fract_f32 %0, %1":"=v"(r):"v"(x)); return r; }
__device__ __forceinline__ float hw_sin(float rev){ float f = hw_fract(rev); float r; asm("v_sin_f32 %0, %1":"=v"(r):"v"(f)); return r; }
__device__ __forceinline__ float hw_exp2(float x){ float r; asm("v_exp_f32 %0, %1":"=v"(r):"v"(x)); return r; }
__device__ __forceinline__ float hw_rcp(float x){ float r; asm("v_rcp_f32 %0, %1":"=v"(r):"v"(x)); return r; }
__device__ __forceinline__ float sigmoidf_hw(float a){
  return hw_rcp(1.f + hw_exp2(-a * LOG2E));
}
// wave64 sum-reduce entirely in the VALU pipe (DPP); total lands in lane 63.
__device__ __forceinline__ float dpp_reduce_add(float x){
  float t;
  asm("v_add_f32 %0, %1, %1 row_shr:1 bound_ctrl:0"  : "=v"(t) : "v"(x));
  asm("v_add_f32 %0, %1, %1 row_shr:2 bound_ctrl:0"  : "=v"(x) : "v"(t));
  asm("v_add_f32 %0, %1, %1 row_shr:4 bound_ctrl:0"  : "=v"(t) : "v"(x));
  asm("v_add_f32 %0, %1, %1 row_shr:8 bound_ctrl:0"  : "=v"(x) : "v"(t));
  asm("v_add_f32 %0, %1, %1 row_bcast:15 row_mask:0xa bound_ctrl:0" : "=v"(t) : "v"(x));
  asm("v_add_f32 %0, %1, %1 row_bcast:31 row_mask:0xc bound_ctrl:0" : "=v"(x) : "v"(t));
  return x;   // valid in lane 63 only
}

// Prep: 4 blocks. b0/b1 -> W1f/W2f frags, b2 -> fused head + biases,
// b3 -> full dt reduction + dtype flag (removes 64-partial fetch + DPP chain
// from every main block).
__global__ void nerf_prep(const void* __restrict__ tmn, const void* __restrict__ tmx,
                          const void* __restrict__ W1, const void* __restrict__ W2,
                          const void* __restrict__ Wout, const void* __restrict__ b1,
                          const void* __restrict__ b2, const void* __restrict__ bout,
                          const void* __restrict__ Wrgb, const void* __restrict__ brgb,
                          void* __restrict__ ws)
{
  const int tid = threadIdx.x;
  const int b   = blockIdx.x;
  const int isbf = detect_bf(tmn);
  unsigned short* w1f = (unsigned short*)ws;
  unsigned short* w2f = w1f + 4096;
  unsigned short* wof = w1f + 8192;
  float* wsf = (float*)((char*)ws + 18432);

  if (b == 0){
    for (int e = tid; e < 4096; e += 256){
      int j = e & 7, n = (e >> 3) & 63, q = e >> 9;
      int k = q*8 + j;
      w1f[e] = (k < 63) ? f2bf(ldin(W1, k*64 + n, isbf)) : (unsigned short)0;
    }
  } else if (b == 1){
    for (int e = tid; e < 4096; e += 256){
      int j = e & 7, n = (e >> 3) & 63, q = e >> 9;
      int k = q*8 + j;
      w2f[e] = f2bf(ldin(W2, k*64 + n, isbf));
    }
  } else if (b == 2){
    for (int e = tid; e < 1024; e += 256){
      int j = e & 7, n = (e >> 3) & 15, q = e >> 7;
      int k = q*8 + j;
      float v = 0.f;
      if (n == 0) v = ldin(Wout, k*17 + 0, isbf);
      else if (n < 4){
        int c = n - 1;
        #pragma unroll
        for (int jj = 0; jj < 16; jj++)
          v += ldin(Wout, k*17 + 1 + jj, isbf) * ldin(Wrgb, jj*3 + c, isbf);
      }
      wof[e] = f2bf(v);
    }
    if (tid < 64){
      wsf[F_B1 + tid] = ldin(b1, tid, isbf);
      wsf[F_B2 + tid] = ldin(b2, tid, isbf);
    }
    if (tid >= 64 && tid < 67){
      int c = tid - 64;
      float v = ldin(brgb, c, isbf);
      #pragma unroll
      for (int jj = 0; jj < 16; jj++)
        v += ldin(bout, 1 + jj, isbf) * ldin(Wrgb, jj*3 + c, isbf);
      wsf[F_BO4 + 1 + c] = v;
    }
    if (tid == 67) wsf[F_BO4] = ldin(bout, 0, isbf);
  } else {
    float s = 0.f;
    for (int i = tid; i < NRAYS; i += 256)
      s += ldin(tmx, i, isbf) - ldin(tmn, i, isbf);
    #pragma unroll
    for (int off = 32; off >= 1; off >>= 1) s += __shfl_down(s, off, 64);
    __shared__ float acc[4];
    if ((tid & 63) == 0) acc[tid >> 6] = s;
    __syncthreads();
    if (tid == 0){
      wsf[F_DT] = (acc[0] + acc[1] + acc[2] + acc[3]) *
                  (1.0f / ((float)NRAYS * (float)NS));
      ((int*)wsf)[F_ISBF] = isbf;
    }
  }
}

// Block = 256 threads = 4 waves = 1 ray. Arena [q=8][m=128][j=8] bf16 = 16 KB.
// launch_bounds(256, 5): same per-wave register budget regime as the proven
// 48-VGPR 128-thread kernel (cap ~102 incl. acc regs) -- (256,8) forced the
// allocator to 32 VGPRs and 417 MB of scratch spills (round-1 regression).
// Actual occupancy is set by the natural allocation (~50-70 regs -> 7-8
// waves/SIMD = 28-32 waves/CU; LDS 8x16KB=128<=160 KB).
// enc is split across all 4 waves: half 0 (waves 0,1) does p + channel 0
// (q0..q2 incl. the s1_0 boundary element), half 1 (waves 2,3) does channels
// 1,2 (q3..q7). Halves the enc serial chain and its register footprint.
// Each wave owns a 32-row GEMM strip (m0 = wid*32): layer D-writes and
// next-layer B-reads stay wave-private -> no barriers in the layer chain.
__global__ __launch_bounds__(256, 5)
void nerf_main(const void* __restrict__ ox, const void* __restrict__ oy,
               const void* __restrict__ oz, const void* __restrict__ dx,
               const void* __restrict__ dy, const void* __restrict__ dz,
               const void* __restrict__ tmn, const void* __restrict__ tmx,
               const void* __restrict__ ws, void* __restrict__ out)
{
  __shared__ __align__(16) char arena[16384];  // bf16 act -> fp32 O overlay (slab0)

  const int tid  = threadIdx.x;
  const int wid  = tid >> 6;
  const int lane = tid & 63;
  const int quad = lane >> 4;
  const int col  = lane & 15;
  const int m0   = wid * 32;
  const int m    = tid & 127;     // sample index for enc/epilogue
  const int half = tid >> 7;

  const unsigned short* gW  = (const unsigned short*)ws;
  const float* wsf = (const float*)((const char*)ws + 18432);
  const int   isbf = ((const int*)wsf)[F_ISBF];
  const float dtv  = wsf[F_DT];

  const int ray = blockIdx.x;
  unsigned short* sA = (unsigned short*)arena;   // idx (q*128+m)*8+j

  // ---- positional encoding, split across halves ----
  {
    float tmin = ldin(tmn, ray, isbf);
    float tmax = ldin(tmx, ray, isbf);
    float t = tmin + ((float)m * (1.0f/127.0f)) * (tmax - tmin);
    if (half == 0){
      // p + channel 0 -> enc[0..23] (23 = sin(p1) boundary element)
      float p0 = ldin(ox, ray, isbf) + ldin(dx, ray, isbf) * t;
      float p1 = ldin(oy, ray, isbf) + ldin(dy, ray, isbf) * t;
      float p2 = ldin(oz, ray, isbf) + ldin(dz, ray, isbf) * t;
      float s[10], c[10];
      float rv = p0 * INV2PI;
      s[0] = hw_sin(rv); c[0] = hw_sin(rv + 0.25f);
      #pragma unroll
      for (int l = 1; l < 10; l++){
        s[l] = 2.f*s[l-1]*c[l-1];
        c[l] = c[l-1]*c[l-1] - s[l-1]*s[l-1];
      }
      float s1_0 = hw_sin(p1 * INV2PI);
      uint4 w;
      w.x = cvtpk(p0, p1);   w.y = cvtpk(p2, s[0]);
      w.z = cvtpk(s[1],s[2]); w.w = cvtpk(s[3],s[4]);
      *(uint4*)(sA + (0*128 + m)*8) = w;
      w.x = cvtpk(s[5],s[6]); w.y = cvtpk(s[7],s[8]);
      w.z = cvtpk(s[9],c[0]); w.w = cvtpk(c[1],c[2]);
      *(uint4*)(sA + (1*128 + m)*8) = w;
      w.x = cvtpk(c[3],c[4]); w.y = cvtpk(c[5],c[6]);
      w.z = cvtpk(c[7],c[8]); w.w = cvtpk(c[9],s1_0);
      *(uint4*)(sA + (2*128 + m)*8) = w;
    } else {
      // channels 1,2 -> enc[24..63]
      float p1 = ldin(oy, ray, isbf) + ldin(dy, ray, isbf) * t;
      float p2 = ldin(oz, ray, isbf) + ldin(dz, ray, isbf) * t;
      float s1[10], c1[10], s2[10], c2[10];
      float rv1 = p1 * INV2PI;
      s1[0] = hw_sin(rv1); c1[0] = hw_sin(rv1 + 0.25f);
      #pragma unroll
      for (int l = 1; l < 10; l++){
        s1[l] = 2.f*s1[l-1]*c1[l-1];
        c1[l] = c1[l-1]*c1[l-1] - s1[l-1]*s1[l-1];
      }
      float rv2 = p2 * INV2PI;
      s2[0] = hw_sin(rv2); c2[0] = hw_sin(rv2 + 0.25f);
      #pragma unroll
      for (int l = 1; l < 10; l++){
        s2[l] = 2.f*s2[l-1]*c2[l-1];
        c2[l] = c2[l-1]*c2[l-1] - s2[l-1]*s2[l-1];
      }
      uint4 w;
      w.x = cvtpk(s1[1],s1[2]); w.y = cvtpk(s1[3],s1[4]);
      w.z = cvtpk(s1[5],s1[6]); w.w = cvtpk(s1[7],s1[8]);
      *(uint4*)(sA + (3*128 + m)*8) = w;
      w.x = cvtpk(s1[9],c1[0]); w.y = cvtpk(c1[1],c1[2]);
      w.z = cvtpk(c1[3],c1[4]); w.w = cvtpk(c1[5],c1[6]);
      *(uint4*)(sA + (4*128 + m)*8) = w;
      w.x = cvtpk(c1[7],c1[8]); w.y = cvtpk(c1[9],s2[0]);
      w.z = cvtpk(s2[1],s2[2]); w.w = cvtpk(s2[3],s2[4]);
      *(uint4*)(sA + (5*128 + m)*8) = w;
      w.x = cvtpk(s2[5],s2[6]); w.y = cvtpk(s2[7],s2[8]);
      w.z = cvtpk(s2[9],c2[0]); w.w = cvtpk(c2[1],c2[2]);
      *(uint4*)(sA + (6*128 + m)*8) = w;
      w.x = cvtpk(c2[3],c2[4]); w.y = cvtpk(c2[5],c2[6]);
      w.z = cvtpk(c2[7],c2[8]); w.w = cvtpk(c2[9], 0.f);
      *(uint4*)(sA + (7*128 + m)*8) = w;
    }
  }
  __syncthreads();   // every wave reads all q rows of its strip

  // ---- hidden layers: weights direct from global (L1-hot), bias in C-init ----
  #pragma unroll
  for (int layer = 0; layer < 2; layer++){
    const unsigned short* Wf = gW + layer*4096;
    const float* bptr = wsf + (layer ? F_B2 : F_B1);
    short8 wf[8];
    f32x4 bia[4];
    #pragma unroll
    for (int nt = 0; nt < 4; nt++){
      wf[nt*2]   = *(const short8*)(Wf + ((quad    )*64 + nt*16 + col)*8);
      wf[nt*2+1] = *(const short8*)(Wf + ((quad + 4)*64 + nt*16 + col)*8);
      bia[nt]    = *(const f32x4*)(bptr + nt*16 + quad*4);
    }
    #pragma unroll
    for (int mt = 0; mt < 2; mt++){
      const int mm = m0 + mt*16 + col;
      short8 h0 = *(const short8*)(sA + ((quad    )*128 + mm)*8);
      short8 h1 = *(const short8*)(sA + ((quad + 4)*128 + mm)*8);
      #pragma unroll
      for (int nt = 0; nt < 4; nt++){
        f32x4 c = bia[nt];
        c = __builtin_amdgcn_mfma_f32_16x16x32_bf16(wf[nt*2],   h0, c, 0, 0, 0);
        c = __builtin_amdgcn_mfma_f32_16x16x32_bf16(wf[nt*2+1], h1, c, 0, 0, 0);
        uint2 pw;
        pw.x = cvtpk(fmaxf(c[0], 0.f), fmaxf(c[1], 0.f));
        pw.y = cvtpk(fmaxf(c[2], 0.f), fmaxf(c[3], 0.f));
        const int qw = nt*2 + (quad >> 1);
        *(uint2*)(sA + (qw*128 + mm)*8 + (quad & 1)*4) = pw;
      }
    }
    // no barrier between layers: rows are wave-private
  }

  // ---- fused output head: 64 -> {sigma_pre, r_pre, g_pre, b_pre} ----
  {
    const unsigned short* Wo = gW + 8192;
    short8 wo0 = *(const short8*)(Wo + ((quad    )*16 + col)*8);
    short8 wo1 = *(const short8*)(Wo + ((quad + 4)*16 + col)*8);
    f32x4 bo4 = {0.f, 0.f, 0.f, 0.f};
    if (quad == 0) bo4 = *(const f32x4*)(wsf + F_BO4);
    float* Of = (float*)arena;            // overlays slab0 (read-before-write per mt)
    #pragma unroll
    for (int mt = 0; mt < 2; mt++){
      const int mm = m0 + mt*16 + col;
      short8 h0 = *(const short8*)(sA + ((quad    )*128 + mm)*8);
      short8 h1 = *(const short8*)(sA + ((quad + 4)*128 + mm)*8);
      f32x4 c = bo4;
      c = __builtin_amdgcn_mfma_f32_16x16x32_bf16(wo0, h0, c, 0, 0, 0);
      c = __builtin_amdgcn_mfma_f32_16x16x32_bf16(wo1, h1, c, 0, 0, 0);
      if (quad == 0) *(f32x4*)(Of + mm*4) = c;
    }
  }
  __syncthreads();   // all head LDS reads done before aux overlays slab2

  // ---- per-sample epilogue (threads 0..127 = samples; dt precomputed) ----
  const float* Of = (const float*)arena;
  float* aux = (float*)(arena + 4096);   // dead slab2: [0]=P0, [4..11]=xr, [12]=Tout
  float v = 0.f, alpha = 0.f, rc = 0.f, gc = 0.f, bc = 0.f;
  if (tid < 128){
    f32x4 o = *(const f32x4*)(Of + tid*4);
    float sigma = fmaxf(o[0], 0.f);
    float e2 = hw_exp2(-sigma * dtv * LOG2E);    // = 1 - alpha
    alpha = 1.f - e2;
    rc = sigmoidf_hw(o[1]);
    gc = sigmoidf_hw(o[2]);
    bc = sigmoidf_hw(o[3]);

    v = e2 + 1e-10f;
    #pragma unroll
    for (int off = 1; off < 64; off <<= 1){
      float tt = __shfl_up(v, off, 64);
      v = (lane >= off) ? v * tt : v;
    }
    if (wid == 0 && lane == 63) aux[0] = v;      // product of first 64 samples
  }
  __syncthreads();
  if (tid < 128){
    const float P0 = aux[0];
    float vfull = wid ? v * P0 : v;              // inclusive cumprod over full ray
    float tp = __shfl_up(vfull, 1, 64);
    float T = (lane == 0) ? (wid ? P0 : 1.f) : tp;
    float w = (T > 1e-4f) ? T * alpha : 0.f;
    float sr = dpp_reduce_add(w * rc);           // totals in lane 63
    float sg = dpp_reduce_add(w * gc);
    float sb = dpp_reduce_add(w * bc);
    if (lane == 63){
      aux[4 + wid*4] = sr; aux[5 + wid*4] = sg; aux[6 + wid*4] = sb;
      if (wid == 1) aux[12] = vfull;             // trans[:, -1]
    }
  }
  __syncthreads();
  if (tid == 0){
    float rr = aux[4] + aux[8], gg = aux[5] + aux[9], bb = aux[6] + aux[10];
    float Tout = aux[12];
    if (isbf){
      unsigned short* ob = (unsigned short*)out;
      ob[ray*3 + 0]     = f2bf(rr);
      ob[ray*3 + 1]     = f2bf(gg);
      ob[ray*3 + 2]     = f2bf(bb);
      ob[3*NRAYS + ray] = f2bf(Tout);
    } else {
      float* of = (float*)out;
      of[ray*3 + 0]     = rr;
      of[ray*3 + 1]     = gg;
      of[ray*3 + 2]     = bb;
      of[3*NRAYS + ray] = Tout;
    }
  }
}

extern "C" void kernel_launch(void* const* d_in, const int* in_sizes, int n_in,
                              void* d_out, int out_size, void* d_ws, size_t ws_size,
                              hipStream_t stream)
{
  nerf_prep<<<4, 256, 0, stream>>>(d_in[6], d_in[7], d_in[8], d_in[10], d_in[12],
                                   d_in[9], d_in[11], d_in[13], d_in[14], d_in[15],
                                   d_ws);
  nerf_main<<<NRAYS, 256, 0, stream>>>(d_in[0], d_in[1], d_in[2], d_in[3],
                                       d_in[4], d_in[5], d_in[6], d_in[7],
                                       d_ws, d_out);
}

// Round 3
// 160.092 us; speedup vs baseline: 1.5077x; 1.0708x over previous
//
#include <hip/hip_runtime.h>

typedef short short8 __attribute__((ext_vector_type(8)));
typedef float f32x4 __attribute__((ext_vector_type(4)));

#define NRAYS 16384
#define NS    128
#define INV2PI 0.15915494309189535f
#define LOG2E  1.4426950408889634f

// ws layout (bytes):
//   [0,8192)      W1f  u16[4096]  frag: elem(q,n,j)=W1[k=q*8+j][n]
//   [8192,16384)  W2f  u16[4096]
//   [16384,18432) Wof  u16[1024]  fused head: n=0 sigma, n=1..3 W_out[:,1:]@W_rgb
//   [18432,19008) wsf  float[144] (F_* indices)
#define F_B1   0
#define F_B2   64
#define F_BO4  128   // {b_out[0], bc0, bc1, bc2}
#define F_DT   132   // finalized dt = mean(tmax-tmin)/S  (prep block 3)
#define F_ISBF 133   // int: input dtype flag (prep block 3)

__device__ __forceinline__ float bf2f(unsigned short u){
  union { unsigned int i; float f; } v; v.i = ((unsigned int)u) << 16; return v.f;
}
__device__ __forceinline__ unsigned short f2bf(float f){   // RNE
  union { unsigned int i; float f; } v; v.f = f;
  unsigned int i = v.i;
  unsigned int r = i + 0x7FFFu + ((i >> 16) & 1u);
  return (unsigned short)(r >> 16);
}
// hardware packed f32x2 -> bf16x2 (RNE, single VOP3)
__device__ __forceinline__ unsigned cvtpk(float a, float b){
  unsigned r; asm("v_cvt_pk_bf16_f32 %0, %1, %2" : "=v"(r) : "v"(a), "v"(b));
  return r;
}
__device__ __forceinline__ float ldin(const void* p, int i, int isbf){
  return isbf ? bf2f(((const unsigned short*)p)[i]) : ((const float*)p)[i];
}
// input dtype detection: even u16 halves of tmn are ~2.0 iff inputs are bf16
__device__ __forceinline__ int detect_bf(const void* tmn){
  const unsigned short* q = (const unsigned short*)tmn;
  int ok = 1;
  #pragma unroll
  for (int i = 0; i < 8; i++){
    float v = bf2f(q[2*i]);
    ok &= (v > 1.5f && v < 2.7f) ? 1 : 0;
  }
  return ok;
}
__device__ __forceinline__ float hw_fract(float x){ float r; asm("v_fract_f32 %0, %1":"=v"(r):"v"(x)); return r; }
__device__ __forceinline__ float hw_sin(float rev){ float f = hw_fract(rev); float r; asm("v_sin_f32 %0, %1":"=v"(r):"v"(f)); return r; }
__device__ __forceinline__ float hw_exp2(float x){ float r; asm("v_exp_f32 %0, %1":"=v"(r):"v"(x)); return r; }
__device__ __forceinline__ float hw_rcp(float x){ float r; asm("v_rcp_f32 %0, %1":"=v"(r):"v"(x)); return r; }
__device__ __forceinline__ float sigmoidf_hw(float a){
  return hw_rcp(1.f + hw_exp2(-a * LOG2E));
}
// wave64 sum-reduce entirely in the VALU pipe (DPP); total lands in lane 63.
__device__ __forceinline__ float dpp_reduce_add(float x){
  float t;
  asm("v_add_f32 %0, %1, %1 row_shr:1 bound_ctrl:0"  : "=v"(t) : "v"(x));
  asm("v_add_f32 %0, %1, %1 row_shr:2 bound_ctrl:0"  : "=v"(x) : "v"(t));
  asm("v_add_f32 %0, %1, %1 row_shr:4 bound_ctrl:0"  : "=v"(t) : "v"(x));
  asm("v_add_f32 %0, %1, %1 row_shr:8 bound_ctrl:0"  : "=v"(x) : "v"(t));
  asm("v_add_f32 %0, %1, %1 row_bcast:15 row_mask:0xa bound_ctrl:0" : "=v"(t) : "v"(x));
  asm("v_add_f32 %0, %1, %1 row_bcast:31 row_mask:0xc bound_ctrl:0" : "=v"(x) : "v"(t));
  return x;   // valid in lane 63 only
}

// gfx950 cross-quad register swaps (VALU pipe -- replaces LDS round-trips).
// v_permlane32_swap_b32: dst[32:63] <-> src[0:31]
// v_permlane16_swap_b32: dst[16:31] <-> src[0:15], dst[48:63] <-> src[32:47]
__device__ __forceinline__ void swap32(unsigned &a, unsigned &b){
  asm("v_permlane32_swap_b32 %0, %1" : "+v"(a), "+v"(b));
}
__device__ __forceinline__ void swap16(unsigned &a, unsigned &b){
  asm("v_permlane16_swap_b32 %0, %1" : "+v"(a), "+v"(b));
}
// D->B quad permutation: lane (quad q, col) holds p0/p1 = packed neurons
// {16nt+4q+0..3} (2 bf16/dword) for nt, nt+1. Output: B-frag dwords so lane q
// holds neurons {8q..8q+7} of its col:
//   after swap32: p0=[P0(0),P0(1),P1(0),P1(1)], p1=[P0(2),P0(3),P1(2),P1(3)]
//   after swap16: p0=[P0(0),P0(2),P1(0),P1(2)], p1=[P0(1),P0(3),P1(1),P1(3)]
// frag = {p0.x,p0.y,p1.x,p1.y} -> neurons 8q+0..3, 8q+4..7.  col untouched.
__device__ __forceinline__ uint4 quad_perm(uint2 p0, uint2 p1){
  swap32(p0.x, p1.x); swap32(p0.y, p1.y);
  swap16(p0.x, p1.x); swap16(p0.y, p1.y);
  uint4 u; u.x = p0.x; u.y = p0.y; u.z = p1.x; u.w = p1.y;
  return u;
}
__device__ __forceinline__ short8 as_s8(uint4 v){
  union { uint4 u; short8 s; } x; x.u = v; return x.s;
}

// Prep: 4 blocks. b0/b1 -> W1f/W2f frags, b2 -> fused head + biases,
// b3 -> full dt reduction + dtype flag.
__global__ void nerf_prep(const void* __restrict__ tmn, const void* __restrict__ tmx,
                          const void* __restrict__ W1, const void* __restrict__ W2,
                          const void* __restrict__ Wout, const void* __restrict__ b1,
                          const void* __restrict__ b2, const void* __restrict__ bout,
                          const void* __restrict__ Wrgb, const void* __restrict__ brgb,
                          void* __restrict__ ws)
{
  const int tid = threadIdx.x;
  const int b   = blockIdx.x;
  const int isbf = detect_bf(tmn);
  unsigned short* w1f = (unsigned short*)ws;
  unsigned short* w2f = w1f + 4096;
  unsigned short* wof = w1f + 8192;
  float* wsf = (float*)((char*)ws + 18432);

  if (b == 0){
    for (int e = tid; e < 4096; e += 256){
      int j = e & 7, n = (e >> 3) & 63, q = e >> 9;
      int k = q*8 + j;
      w1f[e] = (k < 63) ? f2bf(ldin(W1, k*64 + n, isbf)) : (unsigned short)0;
    }
  } else if (b == 1){
    for (int e = tid; e < 4096; e += 256){
      int j = e & 7, n = (e >> 3) & 63, q = e >> 9;
      int k = q*8 + j;
      w2f[e] = f2bf(ldin(W2, k*64 + n, isbf));
    }
  } else if (b == 2){
    for (int e = tid; e < 1024; e += 256){
      int j = e & 7, n = (e >> 3) & 15, q = e >> 7;
      int k = q*8 + j;
      float v = 0.f;
      if (n == 0) v = ldin(Wout, k*17 + 0, isbf);
      else if (n < 4){
        int c = n - 1;
        #pragma unroll
        for (int jj = 0; jj < 16; jj++)
          v += ldin(Wout, k*17 + 1 + jj, isbf) * ldin(Wrgb, jj*3 + c, isbf);
      }
      wof[e] = f2bf(v);
    }
    if (tid < 64){
      wsf[F_B1 + tid] = ldin(b1, tid, isbf);
      wsf[F_B2 + tid] = ldin(b2, tid, isbf);
    }
    if (tid >= 64 && tid < 67){
      int c = tid - 64;
      float v = ldin(brgb, c, isbf);
      #pragma unroll
      for (int jj = 0; jj < 16; jj++)
        v += ldin(bout, 1 + jj, isbf) * ldin(Wrgb, jj*3 + c, isbf);
      wsf[F_BO4 + 1 + c] = v;
    }
    if (tid == 67) wsf[F_BO4] = ldin(bout, 0, isbf);
  } else {
    float s = 0.f;
    for (int i = tid; i < NRAYS; i += 256)
      s += ldin(tmx, i, isbf) - ldin(tmn, i, isbf);
    #pragma unroll
    for (int off = 32; off >= 1; off >>= 1) s += __shfl_down(s, off, 64);
    __shared__ float acc[4];
    if ((tid & 63) == 0) acc[tid >> 6] = s;
    __syncthreads();
    if (tid == 0){
      wsf[F_DT] = (acc[0] + acc[1] + acc[2] + acc[3]) *
                  (1.0f / ((float)NRAYS * (float)NS));
      ((int*)wsf)[F_ISBF] = isbf;
    }
  }
}

// Block = 128 threads = 2 waves = 1 ray (round-0 structure: proven best).
// LDS-pipe is the per-CU bottleneck (~1800 LDS cyc/block of ~2600). This
// version deletes ALL inter-layer LDS round-trips: the D-layout -> B-frag
// repack is a pure quad permutation at fixed col, done in-register with
// v_permlane16/32_swap (VALU pipe). Two phases avoid W1+W2 co-residency:
//   phase 1: L1 over mt=0..3, banking L2 B-frags in 32 VGPRs (H0/H1)
//   phase 2: load W2+head into freed regs; L2 -> perm -> head per mt.
// Remaining LDS: enc stage (16w+16r b128), Of (8w+2r), epilogue (~20 ops)
// -- ~600 cyc/block vs ~1800 before.
__global__ __launch_bounds__(128, 4)
void nerf_main(const void* __restrict__ ox, const void* __restrict__ oy,
               const void* __restrict__ oz, const void* __restrict__ dx,
               const void* __restrict__ dy, const void* __restrict__ dz,
               const void* __restrict__ tmn, const void* __restrict__ tmx,
               const void* __restrict__ ws, void* __restrict__ out)
{
  __shared__ __align__(16) char arena[16384];  // bf16 enc -> fp32 O overlay (slab0)

  const int tid  = threadIdx.x;
  const int wid  = tid >> 6;
  const int lane = tid & 63;
  const int quad = lane >> 4;
  const int col  = lane & 15;
  const int m0   = wid * 64;

  const unsigned short* gW  = (const unsigned short*)ws;
  const float* wsf = (const float*)((const char*)ws + 18432);
  const int   isbf = ((const int*)wsf)[F_ISBF];
  const float dtv  = wsf[F_DT];

  const int ray = blockIdx.x;
  unsigned short* sA = (unsigned short*)arena;   // idx (q*128+m)*8+j

  // ---- positional encoding: hw_sin base + doubling recurrence ----
  {
    float tmin = ldin(tmn, ray, isbf);
    float tmax = ldin(tmx, ray, isbf);
    float t = tmin + ((float)tid * (1.0f/127.0f)) * (tmax - tmin);
    float p[3];
    p[0] = ldin(ox, ray, isbf) + ldin(dx, ray, isbf) * t;
    p[1] = ldin(oy, ray, isbf) + ldin(dy, ray, isbf) * t;
    p[2] = ldin(oz, ray, isbf) + ldin(dz, ray, isbf) * t;
    float enc[64];
    enc[0] = p[0]; enc[1] = p[1]; enc[2] = p[2]; enc[63] = 0.f;
    #pragma unroll
    for (int c = 0; c < 3; c++){
      float rv = p[c] * INV2PI;
      const int bix = 3 + c*20;
      float sv = hw_sin(rv);
      float cv = hw_sin(rv + 0.25f);
      enc[bix] = sv; enc[bix+10] = cv;
      #pragma unroll
      for (int l = 1; l < 10; l++){
        float s2 = 2.f*sv*cv;
        float c2 = cv*cv - sv*sv;
        enc[bix+l] = s2; enc[bix+10+l] = c2;
        sv = s2; cv = c2;
      }
    }
    #pragma unroll
    for (int q = 0; q < 8; q++){
      uint4 w;
      w.x = cvtpk(enc[q*8+0], enc[q*8+1]);
      w.y = cvtpk(enc[q*8+2], enc[q*8+3]);
      w.z = cvtpk(enc[q*8+4], enc[q*8+5]);
      w.w = cvtpk(enc[q*8+6], enc[q*8+7]);
      *(uint4*)(sA + (q*128 + tid)*8) = w;
    }
  }
  // no barrier: enc rows are wave-private (wave w writes/reads samples m0..m0+63)

  uint4 H0[4], H1[4];   // banked L2 B-frags (static-indexed, fully unrolled)

  // ---- phase 1: layer 1 (enc from LDS, output kept in registers) ----
  {
    const unsigned short* Wf = gW;
    short8 wf[8];
    f32x4 bia[4];
    #pragma unroll
    for (int nt = 0; nt < 4; nt++){
      wf[nt*2]   = *(const short8*)(Wf + ((quad    )*64 + nt*16 + col)*8);
      wf[nt*2+1] = *(const short8*)(Wf + ((quad + 4)*64 + nt*16 + col)*8);
      bia[nt]    = *(const f32x4*)(wsf + F_B1 + nt*16 + quad*4);
    }
    #pragma unroll
    for (int mt = 0; mt < 4; mt++){
      const int mm = m0 + mt*16 + col;
      short8 h0 = *(const short8*)(sA + ((quad    )*128 + mm)*8);
      short8 h1 = *(const short8*)(sA + ((quad + 4)*128 + mm)*8);
      uint2 P[4];
      #pragma unroll
      for (int nt = 0; nt < 4; nt++){
        f32x4 c = bia[nt];
        c = __builtin_amdgcn_mfma_f32_16x16x32_bf16(wf[nt*2],   h0, c, 0, 0, 0);
        c = __builtin_amdgcn_mfma_f32_16x16x32_bf16(wf[nt*2+1], h1, c, 0, 0, 0);
        P[nt].x = cvtpk(fmaxf(c[0], 0.f), fmaxf(c[1], 0.f));
        P[nt].y = cvtpk(fmaxf(c[2], 0.f), fmaxf(c[3], 0.f));
      }
      H0[mt] = quad_perm(P[0], P[1]);
      H1[mt] = quad_perm(P[2], P[3]);
    }
  }

  // ---- phase 2: layer 2 + fused head, fully in registers ----
  {
    const unsigned short* Wf = gW + 4096;
    short8 wf[8];
    f32x4 bia[4];
    #pragma unroll
    for (int nt = 0; nt < 4; nt++){
      wf[nt*2]   = *(const short8*)(Wf + ((quad    )*64 + nt*16 + col)*8);
      wf[nt*2+1] = *(const short8*)(Wf + ((quad + 4)*64 + nt*16 + col)*8);
      bia[nt]    = *(const f32x4*)(wsf + F_B2 + nt*16 + quad*4);
    }
    const unsigned short* Wo = gW + 8192;
    short8 wo0 = *(const short8*)(Wo + ((quad    )*16 + col)*8);
    short8 wo1 = *(const short8*)(Wo + ((quad + 4)*16 + col)*8);
    f32x4 bo4 = {0.f, 0.f, 0.f, 0.f};
    if (quad == 0) bo4 = *(const f32x4*)(wsf + F_BO4);
    float* Of = (float*)arena;    // overlays enc slab0 rows of OWN wave (dead)
    #pragma unroll
    for (int mt = 0; mt < 4; mt++){
      const int mm = m0 + mt*16 + col;
      short8 h0 = as_s8(H0[mt]);
      short8 h1 = as_s8(H1[mt]);
      uint2 P[4];
      #pragma unroll
      for (int nt = 0; nt < 4; nt++){
        f32x4 c = bia[nt];
        c = __builtin_amdgcn_mfma_f32_16x16x32_bf16(wf[nt*2],   h0, c, 0, 0, 0);
        c = __builtin_amdgcn_mfma_f32_16x16x32_bf16(wf[nt*2+1], h1, c, 0, 0, 0);
        P[nt].x = cvtpk(fmaxf(c[0], 0.f), fmaxf(c[1], 0.f));
        P[nt].y = cvtpk(fmaxf(c[2], 0.f), fmaxf(c[3], 0.f));
      }
      short8 g0 = as_s8(quad_perm(P[0], P[1]));
      short8 g1 = as_s8(quad_perm(P[2], P[3]));
      f32x4 c = bo4;
      c = __builtin_amdgcn_mfma_f32_16x16x32_bf16(wo0, g0, c, 0, 0, 0);
      c = __builtin_amdgcn_mfma_f32_16x16x32_bf16(wo1, g1, c, 0, 0, 0);
      if (quad == 0) *(f32x4*)(Of + mm*4) = c;
    }
  }
  // no barrier before epilogue: thread tid reads Of bytes of its OWN wave
  // (wave LDS ops in program order); aux lives in wave0's dead enc rows and
  // is only cross-read after the syncthreads below.

  // ---- per-sample epilogue ----
  const float* Ofc = (const float*)arena;
  float* aux = (float*)(arena + 4096);   // wave0's dead enc q2 rows m0..3
  f32x4 o = *(const f32x4*)(Ofc + tid*4);
  float sigma = fmaxf(o[0], 0.f);
  float e2 = hw_exp2(-sigma * dtv * LOG2E);    // = 1 - alpha
  float alpha = 1.f - e2;
  float rc = sigmoidf_hw(o[1]);
  float gc = sigmoidf_hw(o[2]);
  float bc = sigmoidf_hw(o[3]);

  float v = e2 + 1e-10f;
  #pragma unroll
  for (int off = 1; off < 64; off <<= 1){
    float tt = __shfl_up(v, off, 64);
    v = (lane >= off) ? v * tt : v;
  }
  if (wid == 0 && lane == 63) aux[0] = v;      // product of first 64 samples
  __syncthreads();
  const float P0 = aux[0];
  float vfull = wid ? v * P0 : v;              // inclusive cumprod over full ray
  float tp = __shfl_up(vfull, 1, 64);
  float T = (lane == 0) ? (wid ? P0 : 1.f) : tp;
  float w = (T > 1e-4f) ? T * alpha : 0.f;
  float sr = dpp_reduce_add(w * rc);           // totals in lane 63
  float sg = dpp_reduce_add(w * gc);
  float sb = dpp_reduce_add(w * bc);
  if (lane == 63){
    aux[4 + wid*4] = sr; aux[5 + wid*4] = sg; aux[6 + wid*4] = sb;
    if (wid == 1) aux[12] = vfull;             // trans[:, -1]
  }
  __syncthreads();
  if (tid == 0){
    float rr = aux[4] + aux[8], gg = aux[5] + aux[9], bb = aux[6] + aux[10];
    float Tout = aux[12];
    if (isbf){
      unsigned short* ob = (unsigned short*)out;
      ob[ray*3 + 0]     = f2bf(rr);
      ob[ray*3 + 1]     = f2bf(gg);
      ob[ray*3 + 2]     = f2bf(bb);
      ob[3*NRAYS + ray] = f2bf(Tout);
    } else {
      float* of = (float*)out;
      of[ray*3 + 0]     = rr;
      of[ray*3 + 1]     = gg;
      of[ray*3 + 2]     = bb;
      of[3*NRAYS + ray] = Tout;
    }
  }
}

extern "C" void kernel_launch(void* const* d_in, const int* in_sizes, int n_in,
                              void* d_out, int out_size, void* d_ws, size_t ws_size,
                              hipStream_t stream)
{
  nerf_prep<<<4, 256, 0, stream>>>(d_in[6], d_in[7], d_in[8], d_in[10], d_in[12],
                                   d_in[9], d_in[11], d_in[13], d_in[14], d_in[15],
                                   d_ws);
  nerf_main<<<NRAYS, 128, 0, stream>>>(d_in[0], d_in[1], d_in[2], d_in[3],
                                       d_in[4], d_in[5], d_in[6], d_in[7],
                                       d_ws, d_out);
}

// Round 6
// 147.224 us; speedup vs baseline: 1.6395x; 1.0874x over previous
//
#include <hip/hip_runtime.h>

typedef short short8 __attribute__((ext_vector_type(8)));
typedef float f32x4 __attribute__((ext_vector_type(4)));

#define NRAYS 16384
#define NS    128
#define INV2PI 0.15915494309189535f
#define LOG2E  1.4426950408889634f

// ws layout (bytes):
//   [0,8192)      W1f  u16[4096]  frag: elem(q,n,j)=W1[k=q*8+j][n]
//   [8192,16384)  W2f  u16[4096]
//   [16384,18432) Wof  u16[1024]  fused head: n=0 sigma, n=1..3 W_out[:,1:]@W_rgb
//   [18432,19008) wsf  float[144] (F_* indices)
//   [19008,19264) partials float[64]
#define F_B1  0
#define F_B2  64
#define F_BO4 128   // {b_out[0], bc0, bc1, bc2}
#define F_NF  144

__device__ __forceinline__ float bf2f(unsigned short u){
  union { unsigned int i; float f; } v; v.i = ((unsigned int)u) << 16; return v.f;
}
__device__ __forceinline__ unsigned short f2bf(float f){   // RNE
  union { unsigned int i; float f; } v; v.f = f;
  unsigned int i = v.i;
  unsigned int r = i + 0x7FFFu + ((i >> 16) & 1u);
  return (unsigned short)(r >> 16);
}
// hardware packed f32x2 -> bf16x2 (RNE, single VOP3)
__device__ __forceinline__ unsigned cvtpk(float a, float b){
  unsigned r; asm("v_cvt_pk_bf16_f32 %0, %1, %2" : "=v"(r) : "v"(a), "v"(b));
  return r;
}
__device__ __forceinline__ float ldin(const void* p, int i, int isbf){
  return isbf ? bf2f(((const unsigned short*)p)[i]) : ((const float*)p)[i];
}
// input dtype detection: even u16 halves of tmn are ~2.0 iff inputs are bf16
__device__ __forceinline__ int detect_bf(const void* tmn){
  const unsigned short* q = (const unsigned short*)tmn;
  int ok = 1;
  #pragma unroll
  for (int i = 0; i < 8; i++){
    float v = bf2f(q[2*i]);
    ok &= (v > 1.5f && v < 2.7f) ? 1 : 0;
  }
  return ok;
}
__device__ __forceinline__ float hw_fract(float x){ float r; asm("v_fract_f32 %0, %1":"=v"(r):"v"(x)); return r; }
__device__ __forceinline__ float hw_sin(float rev){ float f = hw_fract(rev); float r; asm("v_sin_f32 %0, %1":"=v"(r):"v"(f)); return r; }
__device__ __forceinline__ float hw_exp2(float x){ float r; asm("v_exp_f32 %0, %1":"=v"(r):"v"(x)); return r; }
__device__ __forceinline__ float hw_rcp(float x){ float r; asm("v_rcp_f32 %0, %1":"=v"(r):"v"(x)); return r; }
__device__ __forceinline__ float sigmoidf_hw(float a){
  return hw_rcp(1.f + hw_exp2(-a * LOG2E));
}
// wave64 sum-reduce entirely in the VALU pipe (DPP); total lands in lane 63.
// (round-0-proven alternating form)
__device__ __forceinline__ float dpp_reduce_add(float x){
  float t;
  asm("v_add_f32 %0, %1, %1 row_shr:1 bound_ctrl:0"  : "=v"(t) : "v"(x));
  asm("v_add_f32 %0, %1, %1 row_shr:2 bound_ctrl:0"  : "=v"(x) : "v"(t));
  asm("v_add_f32 %0, %1, %1 row_shr:4 bound_ctrl:0"  : "=v"(t) : "v"(x));
  asm("v_add_f32 %0, %1, %1 row_shr:8 bound_ctrl:0"  : "=v"(x) : "v"(t));
  asm("v_add_f32 %0, %1, %1 row_bcast:15 row_mask:0xa bound_ctrl:0" : "=v"(t) : "v"(x));
  asm("v_add_f32 %0, %1, %1 row_bcast:31 row_mask:0xc bound_ctrl:0" : "=v"(x) : "v"(t));
  return x;   // valid in lane 63 only
}

// gfx950 cross-quad register swaps (VALU pipe -- replaces LDS round-trips).
__device__ __forceinline__ void swap32(unsigned &a, unsigned &b){
  asm("v_permlane32_swap_b32 %0, %1" : "+v"(a), "+v"(b));
}
__device__ __forceinline__ void swap16(unsigned &a, unsigned &b){
  asm("v_permlane16_swap_b32 %0, %1" : "+v"(a), "+v"(b));
}
// D->B quad permutation (HW-verified in round 3): lane (quad q, col) holds
// p0/p1 = packed neurons {16nt+4q+0..3} for nt, nt+1; output B-frag dwords so
// lane q holds neurons {8q..8q+7} of its col. col untouched.
__device__ __forceinline__ uint4 quad_perm(uint2 p0, uint2 p1){
  swap32(p0.x, p1.x); swap32(p0.y, p1.y);
  swap16(p0.x, p1.x); swap16(p0.y, p1.y);
  uint4 u; u.x = p0.x; u.y = p0.y; u.z = p1.x; u.w = p1.y;
  return u;
}
__device__ __forceinline__ short8 as_s8(uint4 v){
  union { uint4 u; short8 s; } x; x.u = v; return x.s;
}

// Prep: round-0-proven 67-block parallel form. b<64 -> ray partial sums;
// b64/b65 -> W1f/W2f frags; b66 -> fused head + biases. (The 4-block variant
// with a serial dt block cost ~13us of bench time: R0 gap 78.9 vs R3 91.9.)
__global__ void nerf_prep(const void* __restrict__ tmn, const void* __restrict__ tmx,
                          const void* __restrict__ W1, const void* __restrict__ W2,
                          const void* __restrict__ Wout, const void* __restrict__ b1,
                          const void* __restrict__ b2, const void* __restrict__ bout,
                          const void* __restrict__ Wrgb, const void* __restrict__ brgb,
                          void* __restrict__ ws)
{
  const int tid = threadIdx.x;
  const int b   = blockIdx.x;
  const int isbf = detect_bf(tmn);
  unsigned short* w1f = (unsigned short*)ws;
  unsigned short* w2f = w1f + 4096;
  unsigned short* wof = w1f + 8192;
  float* wsf = (float*)((char*)ws + 18432);
  float* partials = wsf + F_NF;

  if (b < 64){
    const int i = b * 256 + tid;
    float d = ldin(tmx, i, isbf) - ldin(tmn, i, isbf);
    #pragma unroll
    for (int off = 32; off >= 1; off >>= 1) d += __shfl_down(d, off, 64);
    __shared__ float acc[4];
    if ((tid & 63) == 0) acc[tid >> 6] = d;
    __syncthreads();
    if (tid == 0) partials[b] = acc[0] + acc[1] + acc[2] + acc[3];
  } else if (b == 64){
    for (int e = tid; e < 4096; e += 256){
      int j = e & 7, n = (e >> 3) & 63, q = e >> 9;
      int k = q*8 + j;
      w1f[e] = (k < 63) ? f2bf(ldin(W1, k*64 + n, isbf)) : (unsigned short)0;
    }
  } else if (b == 65){
    for (int e = tid; e < 4096; e += 256){
      int j = e & 7, n = (e >> 3) & 63, q = e >> 9;
      int k = q*8 + j;
      w2f[e] = f2bf(ldin(W2, k*64 + n, isbf));
    }
  } else {
    for (int e = tid; e < 1024; e += 256){
      int j = e & 7, n = (e >> 3) & 15, q = e >> 7;
      int k = q*8 + j;
      float v = 0.f;
      if (n == 0) v = ldin(Wout, k*17 + 0, isbf);
      else if (n < 4){
        int c = n - 1;
        #pragma unroll
        for (int jj = 0; jj < 16; jj++)
          v += ldin(Wout, k*17 + 1 + jj, isbf) * ldin(Wrgb, jj*3 + c, isbf);
      }
      wof[e] = f2bf(v);
    }
    if (tid < 64){
      wsf[F_B1 + tid] = ldin(b1, tid, isbf);
      wsf[F_B2 + tid] = ldin(b2, tid, isbf);
    }
    if (tid >= 64 && tid < 67){
      int c = tid - 64;
      float v = ldin(brgb, c, isbf);
      #pragma unroll
      for (int jj = 0; jj < 16; jj++)
        v += ldin(bout, 1 + jj, isbf) * ldin(Wrgb, jj*3 + c, isbf);
      wsf[F_BO4 + 1 + c] = v;
    }
    if (tid == 67) wsf[F_BO4] = ldin(bout, 0, isbf);
  }
}

// Block = 128 threads = 2 waves = 1 ray (round-3 main, proven: 68.2us,
// absmax 0.0039, zero LDS bank conflicts). Permlane GEMM: all inter-layer
// repacks in-register via v_permlane16/32_swap; LDS only for enc staging,
// the Of overlay, and the epilogue aux exchange.
// Changes vs round 3 (both round-0-proven forms): isbf via detect_bf in-main;
// dtv via DPP reduce over the 64 prep partials (load hoisted to kernel top).
__global__ __launch_bounds__(128, 4)
void nerf_main(const void* __restrict__ ox, const void* __restrict__ oy,
               const void* __restrict__ oz, const void* __restrict__ dx,
               const void* __restrict__ dy, const void* __restrict__ dz,
               const void* __restrict__ tmn, const void* __restrict__ tmx,
               const void* __restrict__ ws, void* __restrict__ out)
{
  __shared__ __align__(16) char arena[16384];  // bf16 enc -> fp32 O overlay (slab0)

  const int tid  = threadIdx.x;
  const int wid  = tid >> 6;
  const int lane = tid & 63;
  const int quad = lane >> 4;
  const int col  = lane & 15;
  const int m0   = wid * 64;

  const unsigned short* gW  = (const unsigned short*)ws;
  const float* wsf = (const float*)((const char*)ws + 18432);
  const int isbf = detect_bf(tmn);

  // partials load issued early (L2-hot); DPP chain deferred to the epilogue
  const float pv_raw = wsf[F_NF + lane];

  const int ray = blockIdx.x;
  unsigned short* sA = (unsigned short*)arena;   // idx (q*128+m)*8+j

  // ---- positional encoding: hw_sin base + doubling recurrence ----
  {
    float tmin = ldin(tmn, ray, isbf);
    float tmax = ldin(tmx, ray, isbf);
    float t = tmin + ((float)tid * (1.0f/127.0f)) * (tmax - tmin);
    float p[3];
    p[0] = ldin(ox, ray, isbf) + ldin(dx, ray, isbf) * t;
    p[1] = ldin(oy, ray, isbf) + ldin(dy, ray, isbf) * t;
    p[2] = ldin(oz, ray, isbf) + ldin(dz, ray, isbf) * t;
    float enc[64];
    enc[0] = p[0]; enc[1] = p[1]; enc[2] = p[2]; enc[63] = 0.f;
    #pragma unroll
    for (int c = 0; c < 3; c++){
      float rv = p[c] * INV2PI;
      const int bix = 3 + c*20;
      float sv = hw_sin(rv);
      float cv = hw_sin(rv + 0.25f);
      enc[bix] = sv; enc[bix+10] = cv;
      #pragma unroll
      for (int l = 1; l < 10; l++){
        float s2 = 2.f*sv*cv;
        float c2 = cv*cv - sv*sv;
        enc[bix+l] = s2; enc[bix+10+l] = c2;
        sv = s2; cv = c2;
      }
    }
    #pragma unroll
    for (int q = 0; q < 8; q++){
      uint4 w;
      w.x = cvtpk(enc[q*8+0], enc[q*8+1]);
      w.y = cvtpk(enc[q*8+2], enc[q*8+3]);
      w.z = cvtpk(enc[q*8+4], enc[q*8+5]);
      w.w = cvtpk(enc[q*8+6], enc[q*8+7]);
      *(uint4*)(sA + (q*128 + tid)*8) = w;
    }
  }
  // no barrier: enc rows are wave-private (wave w writes/reads samples m0..m0+63)

  uint4 H0[4], H1[4];   // banked L2 B-frags (static-indexed, fully unrolled)

  // ---- phase 1: layer 1 (enc from LDS, output kept in registers) ----
  {
    const unsigned short* Wf = gW;
    short8 wf[8];
    f32x4 bia[4];
    #pragma unroll
    for (int nt = 0; nt < 4; nt++){
      wf[nt*2]   = *(const short8*)(Wf + ((quad    )*64 + nt*16 + col)*8);
      wf[nt*2+1] = *(const short8*)(Wf + ((quad + 4)*64 + nt*16 + col)*8);
      bia[nt]    = *(const f32x4*)(wsf + F_B1 + nt*16 + quad*4);
    }
    #pragma unroll
    for (int mt = 0; mt < 4; mt++){
      const int mm = m0 + mt*16 + col;
      short8 h0 = *(const short8*)(sA + ((quad    )*128 + mm)*8);
      short8 h1 = *(const short8*)(sA + ((quad + 4)*128 + mm)*8);
      uint2 P[4];
      #pragma unroll
      for (int nt = 0; nt < 4; nt++){
        f32x4 c = bia[nt];
        c = __builtin_amdgcn_mfma_f32_16x16x32_bf16(wf[nt*2],   h0, c, 0, 0, 0);
        c = __builtin_amdgcn_mfma_f32_16x16x32_bf16(wf[nt*2+1], h1, c, 0, 0, 0);
        P[nt].x = cvtpk(fmaxf(c[0], 0.f), fmaxf(c[1], 0.f));
        P[nt].y = cvtpk(fmaxf(c[2], 0.f), fmaxf(c[3], 0.f));
      }
      H0[mt] = quad_perm(P[0], P[1]);
      H1[mt] = quad_perm(P[2], P[3]);
    }
  }

  // ---- phase 2: layer 2 + fused head, fully in registers ----
  {
    const unsigned short* Wf = gW + 4096;
    short8 wf[8];
    f32x4 bia[4];
    #pragma unroll
    for (int nt = 0; nt < 4; nt++){
      wf[nt*2]   = *(const short8*)(Wf + ((quad    )*64 + nt*16 + col)*8);
      wf[nt*2+1] = *(const short8*)(Wf + ((quad + 4)*64 + nt*16 + col)*8);
      bia[nt]    = *(const f32x4*)(wsf + F_B2 + nt*16 + quad*4);
    }
    const unsigned short* Wo = gW + 8192;
    short8 wo0 = *(const short8*)(Wo + ((quad    )*16 + col)*8);
    short8 wo1 = *(const short8*)(Wo + ((quad + 4)*16 + col)*8);
    f32x4 bo4 = {0.f, 0.f, 0.f, 0.f};
    if (quad == 0) bo4 = *(const f32x4*)(wsf + F_BO4);
    float* Of = (float*)arena;    // overlays enc slab0 rows of OWN wave (dead)
    #pragma unroll
    for (int mt = 0; mt < 4; mt++){
      const int mm = m0 + mt*16 + col;
      short8 h0 = as_s8(H0[mt]);
      short8 h1 = as_s8(H1[mt]);
      uint2 P[4];
      #pragma unroll
      for (int nt = 0; nt < 4; nt++){
        f32x4 c = bia[nt];
        c = __builtin_amdgcn_mfma_f32_16x16x32_bf16(wf[nt*2],   h0, c, 0, 0, 0);
        c = __builtin_amdgcn_mfma_f32_16x16x32_bf16(wf[nt*2+1], h1, c, 0, 0, 0);
        P[nt].x = cvtpk(fmaxf(c[0], 0.f), fmaxf(c[1], 0.f));
        P[nt].y = cvtpk(fmaxf(c[2], 0.f), fmaxf(c[3], 0.f));
      }
      short8 g0 = as_s8(quad_perm(P[0], P[1]));
      short8 g1 = as_s8(quad_perm(P[2], P[3]));
      f32x4 c = bo4;
      c = __builtin_amdgcn_mfma_f32_16x16x32_bf16(wo0, g0, c, 0, 0, 0);
      c = __builtin_amdgcn_mfma_f32_16x16x32_bf16(wo1, g1, c, 0, 0, 0);
      if (quad == 0) *(f32x4*)(Of + mm*4) = c;
    }
  }
  // no barrier before epilogue: thread tid reads Of bytes of its OWN wave
  // (wave LDS ops in program order); aux lives in wave0's dead enc rows and
  // is only cross-read after the syncthreads below.

  // ---- dt via DPP reduce over the 64 prep partials (round-0-proven) ----
  float pv = dpp_reduce_add(pv_raw);
  const float dtv = __builtin_amdgcn_readlane(pv, 63) *
                    (1.0f / ((float)NRAYS * (float)NS));

  // ---- per-sample epilogue ----
  const float* Ofc = (const float*)arena;
  float* aux = (float*)(arena + 4096);   // wave0's dead enc q2 rows m0..3
  f32x4 o = *(const f32x4*)(Ofc + tid*4);
  float sigma = fmaxf(o[0], 0.f);
  float e2 = hw_exp2(-sigma * dtv * LOG2E);    // = 1 - alpha
  float alpha = 1.f - e2;
  float rc = sigmoidf_hw(o[1]);
  float gc = sigmoidf_hw(o[2]);
  float bc = sigmoidf_hw(o[3]);

  float v = e2 + 1e-10f;
  #pragma unroll
  for (int off = 1; off < 64; off <<= 1){
    float tt = __shfl_up(v, off, 64);
    v = (lane >= off) ? v * tt : v;
  }
  if (wid == 0 && lane == 63) aux[0] = v;      // product of first 64 samples
  __syncthreads();
  const float P0 = aux[0];
  float vfull = wid ? v * P0 : v;              // inclusive cumprod over full ray
  float tp = __shfl_up(vfull, 1, 64);
  float T = (lane == 0) ? (wid ? P0 : 1.f) : tp;
  float w = (T > 1e-4f) ? T * alpha : 0.f;
  float sr = dpp_reduce_add(w * rc);           // totals in lane 63
  float sg = dpp_reduce_add(w * gc);
  float sb = dpp_reduce_add(w * bc);
  if (lane == 63){
    aux[4 + wid*4] = sr; aux[5 + wid*4] = sg; aux[6 + wid*4] = sb;
    if (wid == 1) aux[12] = vfull;             // trans[:, -1]
  }
  __syncthreads();
  if (tid == 0){
    float rr = aux[4] + aux[8], gg = aux[5] + aux[9], bb = aux[6] + aux[10];
    float Tout = aux[12];
    if (isbf){
      unsigned short* ob = (unsigned short*)out;
      ob[ray*3 + 0]     = f2bf(rr);
      ob[ray*3 + 1]     = f2bf(gg);
      ob[ray*3 + 2]     = f2bf(bb);
      ob[3*NRAYS + ray] = f2bf(Tout);
    } else {
      float* of = (float*)out;
      of[ray*3 + 0]     = rr;
      of[ray*3 + 1]     = gg;
      of[ray*3 + 2]     = bb;
      of[3*NRAYS + ray] = Tout;
    }
  }
}

extern "C" void kernel_launch(void* const* d_in, const int* in_sizes, int n_in,
                              void* d_out, int out_size, void* d_ws, size_t ws_size,
                              hipStream_t stream)
{
  nerf_prep<<<67, 256, 0, stream>>>(d_in[6], d_in[7], d_in[8], d_in[10], d_in[12],
                                    d_in[9], d_in[11], d_in[13], d_in[14], d_in[15],
                                    d_ws);
  nerf_main<<<NRAYS, 128, 0, stream>>>(d_in[0], d_in[1], d_in[2], d_in[3],
                                       d_in[4], d_in[5], d_in[6], d_in[7],
                                       d_ws, d_out);
}

// Round 7
// 140.478 us; speedup vs baseline: 1.7183x; 1.0480x over previous
//
#include <hip/hip_runtime.h>

typedef short short8 __attribute__((ext_vector_type(8)));
typedef float f32x4 __attribute__((ext_vector_type(4)));

#define NRAYS 16384
#define NS    128
#define INV2PI 0.15915494309189535f
#define LOG2E  1.4426950408889634f

// ws layout (bytes):
//   [0,8192)      W1f  u16[4096]  frag: elem(q,n,j)=W1[k=q*8+j][n]
//   [8192,16384)  W2f  u16[4096]
//   [16384,18432) Wof  u16[1024]  fused head: n=0 sigma, n=1..3 W_out[:,1:]@W_rgb
//   [18432,19008) wsf  float[144] (F_* indices)
//   [19008,19264) partials float[64]
#define F_B1   0
#define F_B2   64
#define F_BO4  128   // {b_out[0], bc0, bc1, bc2}
#define F_ISBF 133   // int: input dtype flag (written by prep b66, idempotent)
#define F_NF   144

__device__ __forceinline__ float bf2f(unsigned short u){
  union { unsigned int i; float f; } v; v.i = ((unsigned int)u) << 16; return v.f;
}
__device__ __forceinline__ unsigned short f2bf(float f){   // RNE
  union { unsigned int i; float f; } v; v.f = f;
  unsigned int i = v.i;
  unsigned int r = i + 0x7FFFu + ((i >> 16) & 1u);
  return (unsigned short)(r >> 16);
}
// hardware packed f32x2 -> bf16x2 (RNE, single VOP3)
__device__ __forceinline__ unsigned cvtpk(float a, float b){
  unsigned r; asm("v_cvt_pk_bf16_f32 %0, %1, %2" : "=v"(r) : "v"(a), "v"(b));
  return r;
}
__device__ __forceinline__ float ldin(const void* p, int i, int isbf){
  return isbf ? bf2f(((const unsigned short*)p)[i]) : ((const float*)p)[i];
}
// input dtype detection: even u16 halves of tmn are ~2.0 iff inputs are bf16
// (prep-only now; main reads the F_ISBF flag -- saves ~32 VALU ops/wave)
__device__ __forceinline__ int detect_bf(const void* tmn){
  const unsigned short* q = (const unsigned short*)tmn;
  int ok = 1;
  #pragma unroll
  for (int i = 0; i < 8; i++){
    float v = bf2f(q[2*i]);
    ok &= (v > 1.5f && v < 2.7f) ? 1 : 0;
  }
  return ok;
}
__device__ __forceinline__ float hw_fract(float x){ float r; asm("v_fract_f32 %0, %1":"=v"(r):"v"(x)); return r; }
__device__ __forceinline__ float hw_sin(float rev){ float f = hw_fract(rev); float r; asm("v_sin_f32 %0, %1":"=v"(r):"v"(f)); return r; }
__device__ __forceinline__ float hw_exp2(float x){ float r; asm("v_exp_f32 %0, %1":"=v"(r):"v"(x)); return r; }
__device__ __forceinline__ float hw_rcp(float x){ float r; asm("v_rcp_f32 %0, %1":"=v"(r):"v"(x)); return r; }
__device__ __forceinline__ float sigmoidf_hw(float a){
  return hw_rcp(1.f + hw_exp2(-a * LOG2E));
}
// wave64 sum-reduce entirely in the VALU pipe (DPP); total lands in lane 63.
__device__ __forceinline__ float dpp_reduce_add(float x){
  float t;
  asm("v_add_f32 %0, %1, %1 row_shr:1 bound_ctrl:0"  : "=v"(t) : "v"(x));
  asm("v_add_f32 %0, %1, %1 row_shr:2 bound_ctrl:0"  : "=v"(x) : "v"(t));
  asm("v_add_f32 %0, %1, %1 row_shr:4 bound_ctrl:0"  : "=v"(t) : "v"(x));
  asm("v_add_f32 %0, %1, %1 row_shr:8 bound_ctrl:0"  : "=v"(x) : "v"(t));
  asm("v_add_f32 %0, %1, %1 row_bcast:15 row_mask:0xa bound_ctrl:0" : "=v"(t) : "v"(x));
  asm("v_add_f32 %0, %1, %1 row_bcast:31 row_mask:0xc bound_ctrl:0" : "=v"(x) : "v"(t));
  return x;   // valid in lane 63 only
}

// gfx950 cross-quad register swaps (VALU pipe -- replaces LDS round-trips).
__device__ __forceinline__ void swap32(unsigned &a, unsigned &b){
  asm("v_permlane32_swap_b32 %0, %1" : "+v"(a), "+v"(b));
}
__device__ __forceinline__ void swap16(unsigned &a, unsigned &b){
  asm("v_permlane16_swap_b32 %0, %1" : "+v"(a), "+v"(b));
}
// D->B quad permutation (HW-verified in round 3): lane (quad q, col) holds
// p0/p1 = packed neurons {16nt+4q+0..3} for nt, nt+1; output B-frag dwords so
// lane q holds neurons {8q..8q+7} of its col. col untouched.
__device__ __forceinline__ uint4 quad_perm(uint2 p0, uint2 p1){
  swap32(p0.x, p1.x); swap32(p0.y, p1.y);
  swap16(p0.x, p1.x); swap16(p0.y, p1.y);
  uint4 u; u.x = p0.x; u.y = p0.y; u.z = p1.x; u.w = p1.y;
  return u;
}
__device__ __forceinline__ short8 as_s8(uint4 v){
  union { uint4 u; short8 s; } x; x.u = v; return x.s;
}

// Prep: 67-block parallel form (proven; the 4-block serial variant cost ~13us
// of bench). b<64 -> ray partial sums; b64/b65 -> W1f/W2f frags; b66 -> fused
// head + biases + isbf flag.
__global__ void nerf_prep(const void* __restrict__ tmn, const void* __restrict__ tmx,
                          const void* __restrict__ W1, const void* __restrict__ W2,
                          const void* __restrict__ Wout, const void* __restrict__ b1,
                          const void* __restrict__ b2, const void* __restrict__ bout,
                          const void* __restrict__ Wrgb, const void* __restrict__ brgb,
                          void* __restrict__ ws)
{
  const int tid = threadIdx.x;
  const int b   = blockIdx.x;
  const int isbf = detect_bf(tmn);
  unsigned short* w1f = (unsigned short*)ws;
  unsigned short* w2f = w1f + 4096;
  unsigned short* wof = w1f + 8192;
  float* wsf = (float*)((char*)ws + 18432);
  float* partials = wsf + F_NF;

  if (b < 64){
    const int i = b * 256 + tid;
    float d = ldin(tmx, i, isbf) - ldin(tmn, i, isbf);
    #pragma unroll
    for (int off = 32; off >= 1; off >>= 1) d += __shfl_down(d, off, 64);
    __shared__ float acc[4];
    if ((tid & 63) == 0) acc[tid >> 6] = d;
    __syncthreads();
    if (tid == 0) partials[b] = acc[0] + acc[1] + acc[2] + acc[3];
  } else if (b == 64){
    for (int e = tid; e < 4096; e += 256){
      int j = e & 7, n = (e >> 3) & 63, q = e >> 9;
      int k = q*8 + j;
      w1f[e] = (k < 63) ? f2bf(ldin(W1, k*64 + n, isbf)) : (unsigned short)0;
    }
  } else if (b == 65){
    for (int e = tid; e < 4096; e += 256){
      int j = e & 7, n = (e >> 3) & 63, q = e >> 9;
      int k = q*8 + j;
      w2f[e] = f2bf(ldin(W2, k*64 + n, isbf));
    }
  } else {
    for (int e = tid; e < 1024; e += 256){
      int j = e & 7, n = (e >> 3) & 15, q = e >> 7;
      int k = q*8 + j;
      float v = 0.f;
      if (n == 0) v = ldin(Wout, k*17 + 0, isbf);
      else if (n < 4){
        int c = n - 1;
        #pragma unroll
        for (int jj = 0; jj < 16; jj++)
          v += ldin(Wout, k*17 + 1 + jj, isbf) * ldin(Wrgb, jj*3 + c, isbf);
      }
      wof[e] = f2bf(v);
    }
    if (tid < 64){
      wsf[F_B1 + tid] = ldin(b1, tid, isbf);
      wsf[F_B2 + tid] = ldin(b2, tid, isbf);
    }
    if (tid >= 64 && tid < 67){
      int c = tid - 64;
      float v = ldin(brgb, c, isbf);
      #pragma unroll
      for (int jj = 0; jj < 16; jj++)
        v += ldin(bout, 1 + jj, isbf) * ldin(Wrgb, jj*3 + c, isbf);
      wsf[F_BO4 + 1 + c] = v;
    }
    if (tid == 67) wsf[F_BO4] = ldin(bout, 0, isbf);
    if (tid == 68) ((int*)wsf)[F_ISBF] = isbf;   // idempotent across iterations
  }
}

// Block = 128 threads = 2 waves = 1 ray. Permlane GEMM (round-3-proven):
// all inter-layer repacks in-register via v_permlane16/32_swap; LDS only for
// enc staging, the Of overlay, and the epilogue aux exchange. Zero bank
// conflicts, VGPR 64.
// Round-7 instruction diet (duration tracks VALU op count; slope calibrated
// R3<->R6: ~14 ops/wave ~= 1us): isbf via prep flag (-32 ops), fma-form sin
// recurrence (-27 ops), wave-uniform isbf branch for ray scalars (-20 ops).
__global__ __launch_bounds__(128, 4)
void nerf_main(const void* __restrict__ ox, const void* __restrict__ oy,
               const void* __restrict__ oz, const void* __restrict__ dx,
               const void* __restrict__ dy, const void* __restrict__ dz,
               const void* __restrict__ tmn, const void* __restrict__ tmx,
               const void* __restrict__ ws, void* __restrict__ out)
{
  __shared__ __align__(16) char arena[16384];  // bf16 enc -> fp32 O overlay (slab0)

  const int tid  = threadIdx.x;
  const int wid  = tid >> 6;
  const int lane = tid & 63;
  const int quad = lane >> 4;
  const int col  = lane & 15;
  const int m0   = wid * 64;

  const unsigned short* gW  = (const unsigned short*)ws;
  const float* wsf = (const float*)((const char*)ws + 18432);
  const int isbf = ((const int*)wsf)[F_ISBF];

  const int ray = blockIdx.x;
  unsigned short* sA = (unsigned short*)arena;   // idx (q*128+m)*8+j

  // ---- positional encoding: hw_sin base + fma doubling recurrence ----
  {
    // ray scalars: wave-uniform branch (scalar cbranch, no divergence)
    float rtmin, rtmax, o_x, o_y, o_z, d_x, d_y, d_z;
    if (isbf){
      const unsigned short* p;
      p = (const unsigned short*)tmn; rtmin = bf2f(p[ray]);
      p = (const unsigned short*)tmx; rtmax = bf2f(p[ray]);
      p = (const unsigned short*)ox;  o_x   = bf2f(p[ray]);
      p = (const unsigned short*)oy;  o_y   = bf2f(p[ray]);
      p = (const unsigned short*)oz;  o_z   = bf2f(p[ray]);
      p = (const unsigned short*)dx;  d_x   = bf2f(p[ray]);
      p = (const unsigned short*)dy;  d_y   = bf2f(p[ray]);
      p = (const unsigned short*)dz;  d_z   = bf2f(p[ray]);
    } else {
      rtmin = ((const float*)tmn)[ray];
      rtmax = ((const float*)tmx)[ray];
      o_x   = ((const float*)ox )[ray];
      o_y   = ((const float*)oy )[ray];
      o_z   = ((const float*)oz )[ray];
      d_x   = ((const float*)dx )[ray];
      d_y   = ((const float*)dy )[ray];
      d_z   = ((const float*)dz )[ray];
    }
    float t = rtmin + ((float)tid * (1.0f/127.0f)) * (rtmax - rtmin);
    float p3[3];
    p3[0] = __builtin_fmaf(d_x, t, o_x);
    p3[1] = __builtin_fmaf(d_y, t, o_y);
    p3[2] = __builtin_fmaf(d_z, t, o_z);
    float enc[64];
    enc[0] = p3[0]; enc[1] = p3[1]; enc[2] = p3[2]; enc[63] = 0.f;
    #pragma unroll
    for (int c = 0; c < 3; c++){
      float rv = p3[c] * INV2PI;
      const int bix = 3 + c*20;
      float sv = hw_sin(rv);
      float cv = hw_sin(rv + 0.25f);
      enc[bix] = sv; enc[bix+10] = cv;
      #pragma unroll
      for (int l = 1; l < 10; l++){
        float t1 = sv*cv;
        float s2 = t1 + t1;                       // 2*s*c
        float u  = sv*sv;
        float c2 = __builtin_fmaf(cv, cv, -u);    // c^2 - s^2 (fma form)
        enc[bix+l] = s2; enc[bix+10+l] = c2;
        sv = s2; cv = c2;
      }
    }
    #pragma unroll
    for (int q = 0; q < 8; q++){
      uint4 w;
      w.x = cvtpk(enc[q*8+0], enc[q*8+1]);
      w.y = cvtpk(enc[q*8+2], enc[q*8+3]);
      w.z = cvtpk(enc[q*8+4], enc[q*8+5]);
      w.w = cvtpk(enc[q*8+6], enc[q*8+7]);
      *(uint4*)(sA + (q*128 + tid)*8) = w;
    }
  }
  // no barrier: enc rows are wave-private (wave w writes/reads samples m0..m0+63)

  uint4 H0[4], H1[4];   // banked L2 B-frags (static-indexed, fully unrolled)

  // ---- phase 1: layer 1 (enc from LDS, output kept in registers) ----
  {
    const unsigned short* Wf = gW;
    short8 wf[8];
    f32x4 bia[4];
    #pragma unroll
    for (int nt = 0; nt < 4; nt++){
      wf[nt*2]   = *(const short8*)(Wf + ((quad    )*64 + nt*16 + col)*8);
      wf[nt*2+1] = *(const short8*)(Wf + ((quad + 4)*64 + nt*16 + col)*8);
      bia[nt]    = *(const f32x4*)(wsf + F_B1 + nt*16 + quad*4);
    }
    #pragma unroll
    for (int mt = 0; mt < 4; mt++){
      const int mm = m0 + mt*16 + col;
      short8 h0 = *(const short8*)(sA + ((quad    )*128 + mm)*8);
      short8 h1 = *(const short8*)(sA + ((quad + 4)*128 + mm)*8);
      uint2 P[4];
      #pragma unroll
      for (int nt = 0; nt < 4; nt++){
        f32x4 c = bia[nt];
        c = __builtin_amdgcn_mfma_f32_16x16x32_bf16(wf[nt*2],   h0, c, 0, 0, 0);
        c = __builtin_amdgcn_mfma_f32_16x16x32_bf16(wf[nt*2+1], h1, c, 0, 0, 0);
        P[nt].x = cvtpk(fmaxf(c[0], 0.f), fmaxf(c[1], 0.f));
        P[nt].y = cvtpk(fmaxf(c[2], 0.f), fmaxf(c[3], 0.f));
      }
      H0[mt] = quad_perm(P[0], P[1]);
      H1[mt] = quad_perm(P[2], P[3]);
    }
  }

  // ---- phase 2: layer 2 + fused head, fully in registers ----
  {
    const unsigned short* Wf = gW + 4096;
    short8 wf[8];
    f32x4 bia[4];
    #pragma unroll
    for (int nt = 0; nt < 4; nt++){
      wf[nt*2]   = *(const short8*)(Wf + ((quad    )*64 + nt*16 + col)*8);
      wf[nt*2+1] = *(const short8*)(Wf + ((quad + 4)*64 + nt*16 + col)*8);
      bia[nt]    = *(const f32x4*)(wsf + F_B2 + nt*16 + quad*4);
    }
    const unsigned short* Wo = gW + 8192;
    short8 wo0 = *(const short8*)(Wo + ((quad    )*16 + col)*8);
    short8 wo1 = *(const short8*)(Wo + ((quad + 4)*16 + col)*8);
    f32x4 bo4 = {0.f, 0.f, 0.f, 0.f};
    if (quad == 0) bo4 = *(const f32x4*)(wsf + F_BO4);
    float* Of = (float*)arena;    // overlays enc slab0 rows of OWN wave (dead)
    #pragma unroll
    for (int mt = 0; mt < 4; mt++){
      const int mm = m0 + mt*16 + col;
      short8 h0 = as_s8(H0[mt]);
      short8 h1 = as_s8(H1[mt]);
      uint2 P[4];
      #pragma unroll
      for (int nt = 0; nt < 4; nt++){
        f32x4 c = bia[nt];
        c = __builtin_amdgcn_mfma_f32_16x16x32_bf16(wf[nt*2],   h0, c, 0, 0, 0);
        c = __builtin_amdgcn_mfma_f32_16x16x32_bf16(wf[nt*2+1], h1, c, 0, 0, 0);
        P[nt].x = cvtpk(fmaxf(c[0], 0.f), fmaxf(c[1], 0.f));
        P[nt].y = cvtpk(fmaxf(c[2], 0.f), fmaxf(c[3], 0.f));
      }
      short8 g0 = as_s8(quad_perm(P[0], P[1]));
      short8 g1 = as_s8(quad_perm(P[2], P[3]));
      f32x4 c = bo4;
      c = __builtin_amdgcn_mfma_f32_16x16x32_bf16(wo0, g0, c, 0, 0, 0);
      c = __builtin_amdgcn_mfma_f32_16x16x32_bf16(wo1, g1, c, 0, 0, 0);
      if (quad == 0) *(f32x4*)(Of + mm*4) = c;
    }
  }
  // no barrier before epilogue: thread tid reads Of bytes of its OWN wave
  // (wave LDS ops in program order); aux lives in wave0's dead enc rows and
  // is only cross-read after the syncthreads below.

  // ---- dt via DPP reduce over the 64 prep partials (L2-hot load here so it
  //      overlaps the Of read latency; R0-proven placement) ----
  float pv = dpp_reduce_add(wsf[F_NF + lane]);
  const float dtv = __builtin_amdgcn_readlane(pv, 63) *
                    (1.0f / ((float)NRAYS * (float)NS));

  // ---- per-sample epilogue ----
  const float* Ofc = (const float*)arena;
  float* aux = (float*)(arena + 4096);   // wave0's dead enc q2 rows m0..3
  f32x4 o = *(const f32x4*)(Ofc + tid*4);
  float sigma = fmaxf(o[0], 0.f);
  float e2 = hw_exp2(-sigma * dtv * LOG2E);    // = 1 - alpha
  float alpha = 1.f - e2;
  float rc = sigmoidf_hw(o[1]);
  float gc = sigmoidf_hw(o[2]);
  float bc = sigmoidf_hw(o[3]);

  float v = e2 + 1e-10f;
  #pragma unroll
  for (int off = 1; off < 64; off <<= 1){
    float tt = __shfl_up(v, off, 64);
    v = (lane >= off) ? v * tt : v;
  }
  if (wid == 0 && lane == 63) aux[0] = v;      // product of first 64 samples
  __syncthreads();
  const float P0 = aux[0];
  float vfull = wid ? v * P0 : v;              // inclusive cumprod over full ray
  float tp = __shfl_up(vfull, 1, 64);
  float T = (lane == 0) ? (wid ? P0 : 1.f) : tp;
  float w = (T > 1e-4f) ? T * alpha : 0.f;
  float sr = dpp_reduce_add(w * rc);           // totals in lane 63
  float sg = dpp_reduce_add(w * gc);
  float sb = dpp_reduce_add(w * bc);
  if (lane == 63){
    aux[4 + wid*4] = sr; aux[5 + wid*4] = sg; aux[6 + wid*4] = sb;
    if (wid == 1) aux[12] = vfull;             // trans[:, -1]
  }
  __syncthreads();
  if (tid == 0){
    float rr = aux[4] + aux[8], gg = aux[5] + aux[9], bb = aux[6] + aux[10];
    float Tout = aux[12];
    if (isbf){
      unsigned short* ob = (unsigned short*)out;
      ob[ray*3 + 0]     = f2bf(rr);
      ob[ray*3 + 1]     = f2bf(gg);
      ob[ray*3 + 2]     = f2bf(bb);
      ob[3*NRAYS + ray] = f2bf(Tout);
    } else {
      float* of = (float*)out;
      of[ray*3 + 0]     = rr;
      of[ray*3 + 1]     = gg;
      of[ray*3 + 2]     = bb;
      of[3*NRAYS + ray] = Tout;
    }
  }
}

extern "C" void kernel_launch(void* const* d_in, const int* in_sizes, int n_in,
                              void* d_out, int out_size, void* d_ws, size_t ws_size,
                              hipStream_t stream)
{
  nerf_prep<<<67, 256, 0, stream>>>(d_in[6], d_in[7], d_in[8], d_in[10], d_in[12],
                                    d_in[9], d_in[11], d_in[13], d_in[14], d_in[15],
                                    d_ws);
  nerf_main<<<NRAYS, 128, 0, stream>>>(d_in[0], d_in[1], d_in[2], d_in[3],
                                       d_in[4], d_in[5], d_in[6], d_in[7],
                                       d_ws, d_out);
}

// Round 9
// 136.873 us; speedup vs baseline: 1.7635x; 1.0263x over previous
//
#include <hip/hip_runtime.h>

typedef short short8 __attribute__((ext_vector_type(8)));
typedef float f32x4 __attribute__((ext_vector_type(4)));

#define NRAYS 16384
#define NS    128
#define INV2PI 0.15915494309189535f
#define LOG2E  1.4426950408889634f

// ws layout (bytes):
//   [0,8192)      W1f  u16[4096]  frag: elem(q,n,j)=W1[k=q*8+j][n]   (identity k)
//   [8192,16384)  W2f  u16[4096]  frag: elem(q,n,j)=W2[kperm(q,j)][n] (pi-permuted)
//   [16384,18432) Wof  u16[1024]  fused head, pi-permuted k rows
//   [18432,19008) wsf  float[144] (F_* indices)
//   [19008,19264) partials float[64]
#define F_B1   0
#define F_B2   64
#define F_BO4  128   // {b_out[0], bc0, bc1, bc2}
#define F_ISBF 133   // int: input dtype flag (written by prep b66, idempotent)
#define F_NF   144

// k-row permutation for W2 and the fused head. Layer-L MFMA output leaves
// lane(q,col) holding neurons {16nt+4q+0..3} (nt=0..3) of sample col. By
// permuting the NEXT layer's weight rows with pi, that register content IS
// the next B-frag: k'=8q+j |-> pi = neurons [4q..4q+3, 16+4q..16+4q+3] for
// the k=0..31 MFMA (q=0..3) and +32 for the k=32..63 MFMA (q=4..7). The MFMA
// k index is a dummy summation variable -- only A/B agreement matters.
// Replaces 64 v_permlane*_swap ops/thread with register renaming.
__device__ __forceinline__ int kperm(int q, int j){
  int qq = q & 3;
  int base = (q < 4) ? 0 : 32;
  return base + ((j < 4) ? (4*qq + j) : (16 + 4*qq + (j - 4)));
}

__device__ __forceinline__ float bf2f(unsigned short u){
  union { unsigned int i; float f; } v; v.i = ((unsigned int)u) << 16; return v.f;
}
__device__ __forceinline__ unsigned short f2bf(float f){   // RNE
  union { unsigned int i; float f; } v; v.f = f;
  unsigned int i = v.i;
  unsigned int r = i + 0x7FFFu + ((i >> 16) & 1u);
  return (unsigned short)(r >> 16);
}
// hardware packed f32x2 -> bf16x2 (RNE, single VOP3)
__device__ __forceinline__ unsigned cvtpk(float a, float b){
  unsigned r; asm("v_cvt_pk_bf16_f32 %0, %1, %2" : "=v"(r) : "v"(a), "v"(b));
  return r;
}
__device__ __forceinline__ float ldin(const void* p, int i, int isbf){
  return isbf ? bf2f(((const unsigned short*)p)[i]) : ((const float*)p)[i];
}
// input dtype detection: even u16 halves of tmn are ~2.0 iff inputs are bf16
__device__ __forceinline__ int detect_bf(const void* tmn){
  const unsigned short* q = (const unsigned short*)tmn;
  int ok = 1;
  #pragma unroll
  for (int i = 0; i < 8; i++){
    float v = bf2f(q[2*i]);
    ok &= (v > 1.5f && v < 2.7f) ? 1 : 0;
  }
  return ok;
}
__device__ __forceinline__ float hw_fract(float x){ float r; asm("v_fract_f32 %0, %1":"=v"(r):"v"(x)); return r; }
__device__ __forceinline__ float hw_sin(float rev){ float f = hw_fract(rev); float r; asm("v_sin_f32 %0, %1":"=v"(r):"v"(f)); return r; }
__device__ __forceinline__ float hw_exp2(float x){ float r; asm("v_exp_f32 %0, %1":"=v"(r):"v"(x)); return r; }
__device__ __forceinline__ float hw_rcp(float x){ float r; asm("v_rcp_f32 %0, %1":"=v"(r):"v"(x)); return r; }
__device__ __forceinline__ float sigmoidf_hw(float a){
  return hw_rcp(1.f + hw_exp2(-a * LOG2E));
}
// wave64 sum-reduce entirely in the VALU pipe (DPP); total lands in lane 63.
__device__ __forceinline__ float dpp_reduce_add(float x){
  float t;
  asm("v_add_f32 %0, %1, %1 row_shr:1 bound_ctrl:0"  : "=v"(t) : "v"(x));
  asm("v_add_f32 %0, %1, %1 row_shr:2 bound_ctrl:0"  : "=v"(x) : "v"(t));
  asm("v_add_f32 %0, %1, %1 row_shr:4 bound_ctrl:0"  : "=v"(t) : "v"(x));
  asm("v_add_f32 %0, %1, %1 row_shr:8 bound_ctrl:0"  : "=v"(x) : "v"(t));
  asm("v_add_f32 %0, %1, %1 row_bcast:15 row_mask:0xa bound_ctrl:0" : "=v"(t) : "v"(x));
  asm("v_add_f32 %0, %1, %1 row_bcast:31 row_mask:0xc bound_ctrl:0" : "=v"(x) : "v"(t));
  return x;   // valid in lane 63 only
}

__device__ __forceinline__ short8 as_s8(uint4 v){
  union { uint4 u; short8 s; } x; x.u = v; return x.s;
}

// Prep: 67-block parallel form (proven). b<64 -> ray partial sums; b64 -> W1f
// (identity k); b65 -> W2f (pi-permuted k); b66 -> fused head (pi-permuted k)
// + biases + isbf flag.
__global__ void nerf_prep(const void* __restrict__ tmn, const void* __restrict__ tmx,
                          const void* __restrict__ W1, const void* __restrict__ W2,
                          const void* __restrict__ Wout, const void* __restrict__ b1,
                          const void* __restrict__ b2, const void* __restrict__ bout,
                          const void* __restrict__ Wrgb, const void* __restrict__ brgb,
                          void* __restrict__ ws)
{
  const int tid = threadIdx.x;
  const int b   = blockIdx.x;
  const int isbf = detect_bf(tmn);
  unsigned short* w1f = (unsigned short*)ws;
  unsigned short* w2f = w1f + 4096;
  unsigned short* wof = w1f + 8192;
  float* wsf = (float*)((char*)ws + 18432);
  float* partials = wsf + F_NF;

  if (b < 64){
    const int i = b * 256 + tid;
    float d = ldin(tmx, i, isbf) - ldin(tmn, i, isbf);
    #pragma unroll
    for (int off = 32; off >= 1; off >>= 1) d += __shfl_down(d, off, 64);
    __shared__ float acc[4];
    if ((tid & 63) == 0) acc[tid >> 6] = d;
    __syncthreads();
    if (tid == 0) partials[b] = acc[0] + acc[1] + acc[2] + acc[3];
  } else if (b == 64){
    for (int e = tid; e < 4096; e += 256){
      int j = e & 7, n = (e >> 3) & 63, q = e >> 9;
      int k = q*8 + j;                           // identity: input is enc
      w1f[e] = (k < 63) ? f2bf(ldin(W1, k*64 + n, isbf)) : (unsigned short)0;
    }
  } else if (b == 65){
    for (int e = tid; e < 4096; e += 256){
      int j = e & 7, n = (e >> 3) & 63, q = e >> 9;
      int k = kperm(q, j);                       // pi: input is layer-1 D-layout
      w2f[e] = f2bf(ldin(W2, k*64 + n, isbf));
    }
  } else {
    for (int e = tid; e < 1024; e += 256){
      int j = e & 7, n = (e >> 3) & 15, q = e >> 7;
      int k = kperm(q, j);                       // pi: input is layer-2 D-layout
      float v = 0.f;
      if (n == 0) v = ldin(Wout, k*17 + 0, isbf);
      else if (n < 4){
        int c = n - 1;
        #pragma unroll
        for (int jj = 0; jj < 16; jj++)
          v += ldin(Wout, k*17 + 1 + jj, isbf) * ldin(Wrgb, jj*3 + c, isbf);
      }
      wof[e] = f2bf(v);
    }
    if (tid < 64){
      wsf[F_B1 + tid] = ldin(b1, tid, isbf);     // bias: output neurons, no pi
      wsf[F_B2 + tid] = ldin(b2, tid, isbf);
    }
    if (tid >= 64 && tid < 67){
      int c = tid - 64;
      float v = ldin(brgb, c, isbf);
      #pragma unroll
      for (int jj = 0; jj < 16; jj++)
        v += ldin(bout, 1 + jj, isbf) * ldin(Wrgb, jj*3 + c, isbf);
      wsf[F_BO4 + 1 + c] = v;
    }
    if (tid == 67) wsf[F_BO4] = ldin(bout, 0, isbf);
    if (tid == 68) ((int*)wsf)[F_ISBF] = isbf;   // idempotent across iterations
  }
}

// Block = 128 threads = 2 waves = 1 ray. Permutation-free GEMM chain: the
// inter-layer repack is absorbed into prep's weight-row permutation (kperm),
// so layer-L's D registers ARE layer-L+1's B-frag -- zero permlane ops
// (round 3-7 spent 64 v_permlane*_swap/thread on this). LDS only for enc
// staging, the Of overlay, and the epilogue aux exchange.
__global__ __launch_bounds__(128, 4)
void nerf_main(const void* __restrict__ ox, const void* __restrict__ oy,
               const void* __restrict__ oz, const void* __restrict__ dx,
               const void* __restrict__ dy, const void* __restrict__ dz,
               const void* __restrict__ tmn, const void* __restrict__ tmx,
               const void* __restrict__ ws, void* __restrict__ out)
{
  __shared__ __align__(16) char arena[16384];  // bf16 enc -> fp32 O overlay (slab0)

  const int tid  = threadIdx.x;
  const int wid  = tid >> 6;
  const int lane = tid & 63;
  const int quad = lane >> 4;
  const int col  = lane & 15;
  const int m0   = wid * 64;

  const unsigned short* gW  = (const unsigned short*)ws;
  const float* wsf = (const float*)((const char*)ws + 18432);
  const int isbf = ((const int*)wsf)[F_ISBF];

  const int ray = blockIdx.x;
  unsigned short* sA = (unsigned short*)arena;   // idx (q*128+m)*8+j

  // ---- positional encoding: hw_sin base + fma doubling recurrence ----
  {
    // ray scalars: wave-uniform branch (scalar cbranch, no divergence)
    float rtmin, rtmax, o_x, o_y, o_z, d_x, d_y, d_z;
    if (isbf){
      const unsigned short* p;
      p = (const unsigned short*)tmn; rtmin = bf2f(p[ray]);
      p = (const unsigned short*)tmx; rtmax = bf2f(p[ray]);
      p = (const unsigned short*)ox;  o_x   = bf2f(p[ray]);
      p = (const unsigned short*)oy;  o_y   = bf2f(p[ray]);
      p = (const unsigned short*)oz;  o_z   = bf2f(p[ray]);
      p = (const unsigned short*)dx;  d_x   = bf2f(p[ray]);
      p = (const unsigned short*)dy;  d_y   = bf2f(p[ray]);
      p = (const unsigned short*)dz;  d_z   = bf2f(p[ray]);
    } else {
      rtmin = ((const float*)tmn)[ray];
      rtmax = ((const float*)tmx)[ray];
      o_x   = ((const float*)ox )[ray];
      o_y   = ((const float*)oy )[ray];
      o_z   = ((const float*)oz )[ray];
      d_x   = ((const float*)dx )[ray];
      d_y   = ((const float*)dy )[ray];
      d_z   = ((const float*)dz )[ray];
    }
    float t = rtmin + ((float)tid * (1.0f/127.0f)) * (rtmax - rtmin);
    float p3[3];
    p3[0] = __builtin_fmaf(d_x, t, o_x);
    p3[1] = __builtin_fmaf(d_y, t, o_y);
    p3[2] = __builtin_fmaf(d_z, t, o_z);
    float enc[64];
    enc[0] = p3[0]; enc[1] = p3[1]; enc[2] = p3[2]; enc[63] = 0.f;
    #pragma unroll
    for (int c = 0; c < 3; c++){
      float rv = p3[c] * INV2PI;
      const int bix = 3 + c*20;
      float sv = hw_sin(rv);
      float cv = hw_sin(rv + 0.25f);
      enc[bix] = sv; enc[bix+10] = cv;
      #pragma unroll
      for (int l = 1; l < 10; l++){
        float t1 = sv*cv;
        float s2 = t1 + t1;                       // 2*s*c
        float u  = sv*sv;
        float c2 = __builtin_fmaf(cv, cv, -u);    // c^2 - s^2 (fma form)
        enc[bix+l] = s2; enc[bix+10+l] = c2;
        sv = s2; cv = c2;
      }
    }
    #pragma unroll
    for (int q = 0; q < 8; q++){
      uint4 w;
      w.x = cvtpk(enc[q*8+0], enc[q*8+1]);
      w.y = cvtpk(enc[q*8+2], enc[q*8+3]);
      w.z = cvtpk(enc[q*8+4], enc[q*8+5]);
      w.w = cvtpk(enc[q*8+6], enc[q*8+7]);
      *(uint4*)(sA + (q*128 + tid)*8) = w;
    }
  }
  // no barrier: enc rows are wave-private (wave w writes/reads samples m0..m0+63)

  uint4 H0[4], H1[4];   // layer-2 B-frags (= layer-1 D regs, renamed)

  // ---- phase 1: layer 1 (enc from LDS, output kept in registers) ----
  {
    const unsigned short* Wf = gW;
    short8 wf[8];
    f32x4 bia[4];
    #pragma unroll
    for (int nt = 0; nt < 4; nt++){
      wf[nt*2]   = *(const short8*)(Wf + ((quad    )*64 + nt*16 + col)*8);
      wf[nt*2+1] = *(const short8*)(Wf + ((quad + 4)*64 + nt*16 + col)*8);
      bia[nt]    = *(const f32x4*)(wsf + F_B1 + nt*16 + quad*4);
    }
    #pragma unroll
    for (int mt = 0; mt < 4; mt++){
      const int mm = m0 + mt*16 + col;
      short8 h0 = *(const short8*)(sA + ((quad    )*128 + mm)*8);
      short8 h1 = *(const short8*)(sA + ((quad + 4)*128 + mm)*8);
      uint2 P[4];
      #pragma unroll
      for (int nt = 0; nt < 4; nt++){
        f32x4 c = bia[nt];
        c = __builtin_amdgcn_mfma_f32_16x16x32_bf16(wf[nt*2],   h0, c, 0, 0, 0);
        c = __builtin_amdgcn_mfma_f32_16x16x32_bf16(wf[nt*2+1], h1, c, 0, 0, 0);
        P[nt].x = cvtpk(fmaxf(c[0], 0.f), fmaxf(c[1], 0.f));
        P[nt].y = cvtpk(fmaxf(c[2], 0.f), fmaxf(c[3], 0.f));
      }
      // kperm absorbs the repack: D regs ARE the next B-frag
      H0[mt].x = P[0].x; H0[mt].y = P[0].y; H0[mt].z = P[1].x; H0[mt].w = P[1].y;
      H1[mt].x = P[2].x; H1[mt].y = P[2].y; H1[mt].z = P[3].x; H1[mt].w = P[3].y;
    }
  }

  // ---- phase 2: layer 2 + fused head, fully in registers ----
  {
    const unsigned short* Wf = gW + 4096;
    short8 wf[8];
    f32x4 bia[4];
    #pragma unroll
    for (int nt = 0; nt < 4; nt++){
      wf[nt*2]   = *(const short8*)(Wf + ((quad    )*64 + nt*16 + col)*8);
      wf[nt*2+1] = *(const short8*)(Wf + ((quad + 4)*64 + nt*16 + col)*8);
      bia[nt]    = *(const f32x4*)(wsf + F_B2 + nt*16 + quad*4);
    }
    const unsigned short* Wo = gW + 8192;
    short8 wo0 = *(const short8*)(Wo + ((quad    )*16 + col)*8);
    short8 wo1 = *(const short8*)(Wo + ((quad + 4)*16 + col)*8);
    f32x4 bo4 = {0.f, 0.f, 0.f, 0.f};
    if (quad == 0) bo4 = *(const f32x4*)(wsf + F_BO4);
    float* Of = (float*)arena;    // overlays enc slab0 rows of OWN wave (dead)
    #pragma unroll
    for (int mt = 0; mt < 4; mt++){
      const int mm = m0 + mt*16 + col;
      short8 h0 = as_s8(H0[mt]);
      short8 h1 = as_s8(H1[mt]);
      uint2 P[4];
      #pragma unroll
      for (int nt = 0; nt < 4; nt++){
        f32x4 c = bia[nt];
        c = __builtin_amdgcn_mfma_f32_16x16x32_bf16(wf[nt*2],   h0, c, 0, 0, 0);
        c = __builtin_amdgcn_mfma_f32_16x16x32_bf16(wf[nt*2+1], h1, c, 0, 0, 0);
        P[nt].x = cvtpk(fmaxf(c[0], 0.f), fmaxf(c[1], 0.f));
        P[nt].y = cvtpk(fmaxf(c[2], 0.f), fmaxf(c[3], 0.f));
      }
      uint4 g0u, g1u;
      g0u.x = P[0].x; g0u.y = P[0].y; g0u.z = P[1].x; g0u.w = P[1].y;
      g1u.x = P[2].x; g1u.y = P[2].y; g1u.z = P[3].x; g1u.w = P[3].y;
      short8 g0 = as_s8(g0u);
      short8 g1 = as_s8(g1u);
      f32x4 c = bo4;
      c = __builtin_amdgcn_mfma_f32_16x16x32_bf16(wo0, g0, c, 0, 0, 0);
      c = __builtin_amdgcn_mfma_f32_16x16x32_bf16(wo1, g1, c, 0, 0, 0);
      if (quad == 0) *(f32x4*)(Of + mm*4) = c;
    }
  }
  // no barrier before epilogue: thread tid reads Of bytes of its OWN wave
  // (wave LDS ops in program order); aux lives in wave0's dead enc rows and
  // is only cross-read after the syncthreads below.

  // ---- dt via DPP reduce over the 64 prep partials (L2-hot) ----
  float pv = dpp_reduce_add(wsf[F_NF + lane]);
  const float dtv = __builtin_amdgcn_readlane(pv, 63) *
                    (1.0f / ((float)NRAYS * (float)NS));

  // ---- per-sample epilogue ----
  const float* Ofc = (const float*)arena;
  float* aux = (float*)(arena + 4096);   // wave0's dead enc q2 rows m0..3
  f32x4 o = *(const f32x4*)(Ofc + tid*4);
  float sigma = fmaxf(o[0], 0.f);
  float e2 = hw_exp2(-sigma * dtv * LOG2E);    // = 1 - alpha
  float alpha = 1.f - e2;
  float rc = sigmoidf_hw(o[1]);
  float gc = sigmoidf_hw(o[2]);
  float bc = sigmoidf_hw(o[3]);

  float v = e2 + 1e-10f;
  #pragma unroll
  for (int off = 1; off < 64; off <<= 1){
    float tt = __shfl_up(v, off, 64);
    v = (lane >= off) ? v * tt : v;
  }
  if (wid == 0 && lane == 63) aux[0] = v;      // product of first 64 samples
  __syncthreads();
  const float P0 = aux[0];
  float vfull = wid ? v * P0 : v;              // inclusive cumprod over full ray
  float tp = __shfl_up(vfull, 1, 64);
  float T = (lane == 0) ? (wid ? P0 : 1.f) : tp;
  float w = (T > 1e-4f) ? T * alpha : 0.f;
  float sr = dpp_reduce_add(w * rc);           // totals in lane 63
  float sg = dpp_reduce_add(w * gc);
  float sb = dpp_reduce_add(w * bc);
  if (lane == 63){
    aux[4 + wid*4] = sr; aux[5 + wid*4] = sg; aux[6 + wid*4] = sb;
    if (wid == 1) aux[12] = vfull;             // trans[:, -1]
  }
  __syncthreads();
  if (tid == 0){
    float rr = aux[4] + aux[8], gg = aux[5] + aux[9], bb = aux[6] + aux[10];
    float Tout = aux[12];
    if (isbf){
      unsigned short* ob = (unsigned short*)out;
      ob[ray*3 + 0]     = f2bf(rr);
      ob[ray*3 + 1]     = f2bf(gg);
      ob[ray*3 + 2]     = f2bf(bb);
      ob[3*NRAYS + ray] = f2bf(Tout);
    } else {
      float* of = (float*)out;
      of[ray*3 + 0]     = rr;
      of[ray*3 + 1]     = gg;
      of[ray*3 + 2]     = bb;
      of[3*NRAYS + ray] = Tout;
    }
  }
}

extern "C" void kernel_launch(void* const* d_in, const int* in_sizes, int n_in,
                              void* d_out, int out_size, void* d_ws, size_t ws_size,
                              hipStream_t stream)
{
  nerf_prep<<<67, 256, 0, stream>>>(d_in[6], d_in[7], d_in[8], d_in[10], d_in[12],
                                    d_in[9], d_in[11], d_in[13], d_in[14], d_in[15],
                                    d_ws);
  nerf_main<<<NRAYS, 128, 0, stream>>>(d_in[0], d_in[1], d_in[2], d_in[3],
                                       d_in[4], d_in[5], d_in[6], d_in[7],
                                       d_ws, d_out);
}